// Round 6
// baseline (523.374 us; speedup 1.0000x reference)
//
#include <hip/hip_runtime.h>
#include <hip/hip_fp16.h>

// ---------------------------------------------------------------------------
// GCN forward: 2x GCNConv(relu) + global_mean_pool + linear
// Strategy: device-built CSR (dst-grouped, src-only payload) reused across
// both layers; GEMMs fold dis[row] into the fp16 epilogue (XW' = dis*X@W),
// so aggregation is an unweighted gather-sum scaled once by dis[dst]:
//   out[d] = relu(dis[d] * (XW'[d] + sum_e XW'[src_e]) + bias)
// R1: single-block scan (232us) -> 3-phase multi-block scan.
// R2: k_agg latency-bound -> multi-edge-group wave agg (171->123us).
// R3: agg 48% HBM, 408MB fetch -> fp16 gathered operand, 16B/lane loads.
// R4: gemm 190us (19% occ, branch-in-loop) -> 64x64 col tiles, 32KB LDS.
// R5: k_build 155MB scattered writes (2 arrays) -> enorm eliminated via
//     dis-folding; build scatters only esrc (4B/edge).
// ---------------------------------------------------------------------------

__global__ void k_init(int* __restrict__ cnt, float* __restrict__ psum,
                       float* __restrict__ pcnt, int n, int psumN, int G) {
  int i = blockIdx.x * 256 + threadIdx.x;
  if (i < n) cnt[i] = 0;
  if (i < psumN) psum[i] = 0.f;
  if (i < G) pcnt[i] = 0.f;
}

__global__ void k_count(const int* __restrict__ dst, int* __restrict__ cnt, int E) {
  int i = blockIdx.x * 256 + threadIdx.x;
  if (i < E) atomicAdd(&cnt[dst[i]], 1);
}

__global__ void k_dis(const int* __restrict__ cnt, float* __restrict__ dis, int n) {
  int i = blockIdx.x * 256 + threadIdx.x;
  if (i < n) dis[i] = rsqrtf((float)(cnt[i] + 1));  // +1 self-loop; deg>=1 always
}

// ---- 3-phase exclusive scan of cnt[0..n) -> rowptr, cursor ---------------
__global__ __launch_bounds__(256) void k_scanA(const int* __restrict__ cnt,
                                               int* __restrict__ bsum, int n) {
  __shared__ int red[256];
  int t = threadIdx.x;
  int base = blockIdx.x * 1024 + t * 4;
  int s = 0;
#pragma unroll
  for (int j = 0; j < 4; ++j) {
    int i = base + j;
    if (i < n) s += cnt[i];
  }
  red[t] = s;
  __syncthreads();
  for (int off = 128; off > 0; off >>= 1) {
    if (t < off) red[t] += red[t + off];
    __syncthreads();
  }
  if (t == 0) bsum[blockIdx.x] = red[0];
}

__global__ __launch_bounds__(256) void k_scanB(const int* __restrict__ bsum,
                                               int* __restrict__ boff, int NB) {
  __shared__ int sh[256];
  int t = threadIdx.x;
  sh[t] = (t < NB) ? bsum[t] : 0;
  __syncthreads();
  for (int off = 1; off < 256; off <<= 1) {
    int v = (t >= off) ? sh[t - off] : 0;
    __syncthreads();
    sh[t] += v;
    __syncthreads();
  }
  if (t < NB) boff[t] = (t == 0) ? 0 : sh[t - 1];
}

__global__ __launch_bounds__(256) void k_scanC(const int* __restrict__ cnt,
                                               const int* __restrict__ boff,
                                               int* __restrict__ rowptr,
                                               int* __restrict__ cursor, int n) {
  __shared__ int sh[256];
  int t = threadIdx.x;
  int base = blockIdx.x * 1024 + t * 4;
  int v[4];
  int s = 0;
#pragma unroll
  for (int j = 0; j < 4; ++j) {
    int i = base + j;
    v[j] = (i < n) ? cnt[i] : 0;
    s += v[j];
  }
  sh[t] = s;
  __syncthreads();
  for (int off = 1; off < 256; off <<= 1) {
    int u = (t >= off) ? sh[t - off] : 0;
    __syncthreads();
    sh[t] += u;
    __syncthreads();
  }
  int run = boff[blockIdx.x] + ((t == 0) ? 0 : sh[t - 1]);
#pragma unroll
  for (int j = 0; j < 4; ++j) {
    int i = base + j;
    if (i < n) {
      rowptr[i] = run;
      cursor[i] = run;
      run += v[j];
    }
  }
}

// scatter only src index; norm is folded into GEMM epilogue + agg epilogue
__global__ void k_build(const int* __restrict__ src, const int* __restrict__ dst,
                        int* __restrict__ cursor, int* __restrict__ esrc, int E) {
  int i = blockIdx.x * 256 + threadIdx.x;
  if (i >= E) return;
  int s = src[i], d = dst[i];
  int slot = atomicAdd(&cursor[d], 1);
  esrc[slot] = s;
}

// out[nrows, COLS] (fp16) = dis[row] * (A[nrows, 128] (fp32) @ W[128, COLS]).
// Block = 64 rows x 64 cols; this block's 64 W-columns staged in LDS
// (32KB -> 5 blocks/CU). 256 thr: 16 col-groups x 16 row-groups, 4 rows/thr.
template <int COLS>
__global__ __launch_bounds__(256) void k_gemm(const float* __restrict__ A,
                                              const float* __restrict__ W,
                                              const float* __restrict__ dis,
                                              __half* __restrict__ out, int nrows) {
  __shared__ float Ws[128 * 64];
  int t = threadIdx.x;
  int cbase = blockIdx.y * 64;
  for (int i = t; i < 128 * 16; i += 256) {
    int k = i >> 4;
    int c = (i & 15) * 4;
    *(float4*)&Ws[k * 64 + c] = *(const float4*)&W[k * COLS + cbase + c];
  }
  __syncthreads();

  int tx = t & 15, ty = t >> 4;
  int row0 = blockIdx.x * 64 + ty * 4;
  int c0 = tx * 4;

  float acc[4][4];
#pragma unroll
  for (int r = 0; r < 4; ++r)
    acc[r][0] = acc[r][1] = acc[r][2] = acc[r][3] = 0.f;

  if (row0 + 4 <= nrows) {
    for (int k = 0; k < 128; k += 4) {
      float4 a0 = *(const float4*)&A[(size_t)(row0 + 0) * 128 + k];
      float4 a1 = *(const float4*)&A[(size_t)(row0 + 1) * 128 + k];
      float4 a2 = *(const float4*)&A[(size_t)(row0 + 2) * 128 + k];
      float4 a3 = *(const float4*)&A[(size_t)(row0 + 3) * 128 + k];
      float4 w0 = *(const float4*)&Ws[(k + 0) * 64 + c0];
      float4 w1 = *(const float4*)&Ws[(k + 1) * 64 + c0];
      float4 w2 = *(const float4*)&Ws[(k + 2) * 64 + c0];
      float4 w3 = *(const float4*)&Ws[(k + 3) * 64 + c0];
#define GEMM_FMA(r, a)                                  \
  acc[r][0] = fmaf(a.x, w0.x, acc[r][0]);               \
  acc[r][1] = fmaf(a.x, w0.y, acc[r][1]);               \
  acc[r][2] = fmaf(a.x, w0.z, acc[r][2]);               \
  acc[r][3] = fmaf(a.x, w0.w, acc[r][3]);               \
  acc[r][0] = fmaf(a.y, w1.x, acc[r][0]);               \
  acc[r][1] = fmaf(a.y, w1.y, acc[r][1]);               \
  acc[r][2] = fmaf(a.y, w1.z, acc[r][2]);               \
  acc[r][3] = fmaf(a.y, w1.w, acc[r][3]);               \
  acc[r][0] = fmaf(a.z, w2.x, acc[r][0]);               \
  acc[r][1] = fmaf(a.z, w2.y, acc[r][1]);               \
  acc[r][2] = fmaf(a.z, w2.z, acc[r][2]);               \
  acc[r][3] = fmaf(a.z, w2.w, acc[r][3]);               \
  acc[r][0] = fmaf(a.w, w3.x, acc[r][0]);               \
  acc[r][1] = fmaf(a.w, w3.y, acc[r][1]);               \
  acc[r][2] = fmaf(a.w, w3.z, acc[r][2]);               \
  acc[r][3] = fmaf(a.w, w3.w, acc[r][3]);
      GEMM_FMA(0, a0)
      GEMM_FMA(1, a1)
      GEMM_FMA(2, a2)
      GEMM_FMA(3, a3)
    }
#pragma unroll
    for (int r = 0; r < 4; ++r) {
      float dn = dis[row0 + r];
      union { __half2 h2[2]; float2 f2; } u;
      u.h2[0] = __floats2half2_rn(acc[r][0] * dn, acc[r][1] * dn);
      u.h2[1] = __floats2half2_rn(acc[r][2] * dn, acc[r][3] * dn);
      *(float2*)&out[(size_t)(row0 + r) * COLS + cbase + c0] = u.f2;
    }
  } else {
    for (int k = 0; k < 128; k += 4) {
      float4 w0 = *(const float4*)&Ws[(k + 0) * 64 + c0];
      float4 w1 = *(const float4*)&Ws[(k + 1) * 64 + c0];
      float4 w2 = *(const float4*)&Ws[(k + 2) * 64 + c0];
      float4 w3 = *(const float4*)&Ws[(k + 3) * 64 + c0];
      for (int r = 0; r < 4; ++r) {
        int row = row0 + r;
        if (row >= nrows) continue;
        float4 a = *(const float4*)&A[(size_t)row * 128 + k];
        GEMM_FMA(r, a)
      }
    }
#pragma unroll
    for (int r = 0; r < 4; ++r) {
      int row = row0 + r;
      if (row < nrows) {
        float dn = dis[row];
        union { __half2 h2[2]; float2 f2; } u;
        u.h2[0] = __floats2half2_rn(acc[r][0] * dn, acc[r][1] * dn);
        u.h2[1] = __floats2half2_rn(acc[r][2] * dn, acc[r][3] * dn);
        *(float2*)&out[(size_t)row * COLS + cbase + c0] = u.f2;
      }
    }
#undef GEMM_FMA
  }
}

// wave per node; COLS/8 lanes per edge-row (16B half8 loads), NG edge groups
// per wave, depth-2 pipeline. H is pre-scaled by dis[src]; validity via
// register weight in {0,1}. out[d] = relu(dis[d]*(H[d]+sum) + bias), fp32.
template <int COLS>
__global__ __launch_bounds__(256) void k_agg(const __half* __restrict__ H,
                                             const int* __restrict__ rowptr,
                                             const int* __restrict__ rowend,
                                             const int* __restrict__ esrc,
                                             const float* __restrict__ dis,
                                             const float* __restrict__ bias,
                                             float* __restrict__ out, int n) {
  constexpr int LPE = COLS / 8;  // lanes per edge-row (16 or 8)
  constexpr int NG = 64 / LPE;   // edge groups per wave (4 or 8)
  int node = (blockIdx.x * 256 + threadIdx.x) >> 6;
  if (node >= n) return;
  int lane = threadIdx.x & 63;
  int group = lane / LPE;
  int c = (lane % LPE) * 8;

  float acc[8];
#pragma unroll
  for (int j = 0; j < 8; ++j) acc[j] = 0.f;

  int beg = rowptr[node], end = rowend[node];
  int e0 = beg + group;
  int e1 = e0 + NG;
  int s0 = 0, s1 = 0;
  float w0 = 0.f, w1 = 0.f;
  if (e0 < end) { s0 = esrc[e0]; w0 = 1.f; }
  if (e1 < end) { s1 = esrc[e1]; w1 = 1.f; }
  while (e0 < end) {
    float4 r0 = *(const float4*)&H[(size_t)s0 * COLS + c];
    float4 r1 = *(const float4*)&H[(size_t)s1 * COLS + c];
    int e2 = e0 + 2 * NG, e3 = e1 + 2 * NG;
    int s2 = 0, s3 = 0;
    float w2 = 0.f, w3 = 0.f;
    if (e2 < end) { s2 = esrc[e2]; w2 = 1.f; }
    if (e3 < end) { s3 = esrc[e3]; w3 = 1.f; }
    {
      union { float4 f4; __half2 h2[4]; } u;
      u.f4 = r0;
#pragma unroll
      for (int j = 0; j < 4; ++j) {
        float2 f = __half22float2(u.h2[j]);
        acc[2 * j + 0] = fmaf(f.x, w0, acc[2 * j + 0]);
        acc[2 * j + 1] = fmaf(f.y, w0, acc[2 * j + 1]);
      }
      u.f4 = r1;
#pragma unroll
      for (int j = 0; j < 4; ++j) {
        float2 f = __half22float2(u.h2[j]);
        acc[2 * j + 0] = fmaf(f.x, w1, acc[2 * j + 0]);
        acc[2 * j + 1] = fmaf(f.y, w1, acc[2 * j + 1]);
      }
    }
    e0 = e2; s0 = s2; w0 = w2;
    e1 = e3; s1 = s3; w1 = w3;
  }
  // combine edge groups (lanes with equal lane%LPE)
#pragma unroll
  for (int m = LPE; m < 64; m <<= 1) {
#pragma unroll
    for (int j = 0; j < 8; ++j) acc[j] += __shfl_xor(acc[j], m, 64);
  }
  if (group == 0) {
    float dn = dis[node];
    union { float4 f4; __half2 h2[4]; } u;
    u.f4 = *(const float4*)&H[(size_t)node * COLS + c];
    float o[8];
#pragma unroll
    for (int j = 0; j < 4; ++j) {
      float2 f = __half22float2(u.h2[j]);
      o[2 * j + 0] = fmaxf(fmaf(acc[2 * j + 0] + f.x, dn, bias[c + 2 * j + 0]), 0.f);
      o[2 * j + 1] = fmaxf(fmaf(acc[2 * j + 1] + f.y, dn, bias[c + 2 * j + 1]), 0.f);
    }
    *(float4*)&out[(size_t)node * COLS + c] = make_float4(o[0], o[1], o[2], o[3]);
    *(float4*)&out[(size_t)node * COLS + c + 4] = make_float4(o[4], o[5], o[6], o[7]);
  }
}

// run-length pooling over sorted batch; 32 nodes per wave, lane = column
__global__ void k_pool(const float* __restrict__ H2, const int* __restrict__ batch,
                       float* __restrict__ psum, float* __restrict__ pcnt, int n) {
  int wv = (blockIdx.x * 256 + threadIdx.x) >> 6;
  int lane = threadIdx.x & 63;
  int start = wv * 32;
  if (start >= n) return;
  int end = min(start + 32, n);
  int curg = batch[start];
  float acc = 0.f;
  int cn = 0;
  for (int i = start; i < end; ++i) {
    int g = batch[i];
    if (g != curg) {
      atomicAdd(&psum[curg * 64 + lane], acc);
      if (lane == 0) atomicAdd(&pcnt[curg], (float)cn);
      acc = 0.f;
      cn = 0;
      curg = g;
    }
    acc += H2[(size_t)i * 64 + lane];
    ++cn;
  }
  atomicAdd(&psum[curg * 64 + lane], acc);
  if (lane == 0) atomicAdd(&pcnt[curg], (float)cn);
}

__global__ void k_final(const float* __restrict__ psum, const float* __restrict__ pcnt,
                        const float* __restrict__ lin_w, const float* __restrict__ lin_b,
                        float* __restrict__ out, int G) {
  int g = blockIdx.x * 64 + threadIdx.x;
  if (g >= G) return;
  float c = fmaxf(pcnt[g], 1.f);
  float s = 0.f;
  for (int i = 0; i < 64; ++i) s += psum[g * 64 + i] * lin_w[i];
  out[g] = s / c + lin_b[0];
}

extern "C" void kernel_launch(void* const* d_in, const int* in_sizes, int n_in,
                              void* d_out, int out_size, void* d_ws, size_t ws_size,
                              hipStream_t stream) {
  const float* x = (const float*)d_in[0];
  const int* edge = (const int*)d_in[1];
  const int* batch = (const int*)d_in[2];
  const float* W1 = (const float*)d_in[3];
  const float* b1 = (const float*)d_in[4];
  const float* W2 = (const float*)d_in[5];
  const float* b2 = (const float*)d_in[6];
  const float* lin_w = (const float*)d_in[7];
  const float* lin_b = (const float*)d_in[8];
  float* out = (float*)d_out;

  const int N = in_sizes[2];
  const int E = in_sizes[1] / 2;
  const int G = out_size;
  const int* esrc_in = edge;       // edge_index[0] = src
  const int* edst_in = edge + E;   // edge_index[1] = dst

  char* w = (char*)d_ws;
  size_t off = 0;
  auto take = [&](size_t bytes) {
    void* p = w + off;
    off += (bytes + 255) & ~(size_t)255;
    return p;
  };
  int* cnt = (int*)take((size_t)N * 4);
  int* rowptr = (int*)take((size_t)N * 4);
  int* cursor = (int*)take((size_t)N * 4);   // after build: cursor[i] == row end
  float* dis = (float*)take((size_t)N * 4);
  int* esrc = (int*)take((size_t)E * 4);
  __half* XW = (__half*)take((size_t)N * 128 * 2);  // fp16; reused as [N,64] layer 2
  float* H1 = (float*)take((size_t)N * 128 * 4);    // fp32; reused as H2 [N,64]
  float* psum = (float*)take((size_t)G * 64 * 4);
  float* pcnt = (float*)take((size_t)G * 4);
  int* bsum = (int*)take(1024 * 4);
  int* boff = (int*)take(1024 * 4);
  (void)ws_size;
  (void)n_in;

  int nb_n = (N + 255) / 256;
  int nb_e = (E + 255) / 256;
  int NB = (N + 1023) / 1024;  // scan blocks (98 for N=100000; must be <= 256)

  k_init<<<nb_n, 256, 0, stream>>>(cnt, psum, pcnt, N, G * 64, G);
  k_count<<<nb_e, 256, 0, stream>>>(edst_in, cnt, E);
  k_dis<<<nb_n, 256, 0, stream>>>(cnt, dis, N);
  k_scanA<<<NB, 256, 0, stream>>>(cnt, bsum, N);
  k_scanB<<<1, 256, 0, stream>>>(bsum, boff, NB);
  k_scanC<<<NB, 256, 0, stream>>>(cnt, boff, rowptr, cursor, N);
  k_build<<<nb_e, 256, 0, stream>>>(esrc_in, edst_in, cursor, esrc, E);

  int gb = (N + 63) / 64;
  int ab = (int)(((size_t)N * 64 + 255) / 256);

  // layer 1: XW = fp16(dis * (x@W1)); H1 = relu(dis*(selfrow+sum) + b1) fp32
  k_gemm<128><<<dim3(gb, 2), 256, 0, stream>>>(x, W1, dis, XW, N);
  k_agg<128><<<ab, 256, 0, stream>>>(XW, rowptr, cursor, esrc, dis, b1, H1, N);

  // layer 2: XW[:, :64] = fp16(dis * (H1@W2)); H2 (into H1 buffer)
  k_gemm<64><<<dim3(gb, 1), 256, 0, stream>>>(H1, W2, dis, XW, N);
  k_agg<64><<<ab, 256, 0, stream>>>(XW, rowptr, cursor, esrc, dis, b2, H1, N);

  // mean-pool + linear head
  int pb = (int)((((size_t)(N + 31) / 32) * 64 + 255) / 256);
  k_pool<<<pb, 256, 0, stream>>>(H1, batch, psum, pcnt, N);
  k_final<<<1, 64, 0, stream>>>(psum, pcnt, lin_w, lin_b, out, G);
}

// Round 7
// 369.781 us; speedup vs baseline: 1.4154x; 1.4154x over previous
//
#include <hip/hip_runtime.h>
#include <hip/hip_fp16.h>

// ---------------------------------------------------------------------------
// GCN forward: 2x GCNConv(relu) + global_mean_pool + linear
// CSR built via two-level bucket multisplit (R7): LDS histograms + per-block
// bucket reservations + per-bucket LDS-cursor build. Kills the random-scatter
// line thrash that made k_count/k_build ~185us (R6: 106MB HBM writes for
// 6.4MB payload = one dirty line per edge, ping-ponged across 8 XCD L2s).
// GEMMs fold dis[row] into fp16 epilogue; agg is unweighted gather-sum
// scaled by dis[dst]:  out[d] = relu(dis[d]*(XW'[d]+sum XW'[src]) + b)
// R1: multi-block scan. R2: multi-edge-group agg. R3: fp16 gather operand.
// R4: 64x64 GEMM tiles. R5: enorm eliminated (dis-folding).
// R6: FAILED enorm removal didn't speed build -> locality is the problem.
// ---------------------------------------------------------------------------

#define DN 512      // dst nodes per bucket
#define DSHIFT 9    // log2(DN)

__global__ void k_init(int* __restrict__ bucket_cnt, float* __restrict__ psum,
                       float* __restrict__ pcnt, int NBK, int psumN, int G) {
  int i = blockIdx.x * 256 + threadIdx.x;
  if (i < NBK) bucket_cnt[i] = 0;
  if (i < psumN) psum[i] = 0.f;
  if (i < G) pcnt[i] = 0.f;
}

// phase 1a: per-block LDS histogram of dst buckets -> global bucket_cnt
__global__ __launch_bounds__(1024) void k_hist(const int* __restrict__ dst,
                                               int* __restrict__ bucket_cnt,
                                               int E, int NBK) {
  __shared__ int h[256];
  int t = threadIdx.x;
  if (t < 256) h[t] = 0;
  __syncthreads();
  int base = blockIdx.x * 4096;
#pragma unroll
  for (int j = 0; j < 4; ++j) {
    int i = base + j * 1024 + t;
    if (i < E) atomicAdd(&h[dst[i] >> DSHIFT], 1);
  }
  __syncthreads();
  if (t < NBK && h[t] > 0) atomicAdd(&bucket_cnt[t], h[t]);
}

// phase 1b: scan bucket counts -> bucket_start, bucket_cursor (NBK <= 256)
__global__ __launch_bounds__(256) void k_bscan(const int* __restrict__ bucket_cnt,
                                               int* __restrict__ bucket_start,
                                               int* __restrict__ bucket_cursor,
                                               int NBK) {
  __shared__ int sh[256];
  int t = threadIdx.x;
  sh[t] = (t < NBK) ? bucket_cnt[t] : 0;
  __syncthreads();
  for (int off = 1; off < 256; off <<= 1) {
    int v = (t >= off) ? sh[t - off] : 0;
    __syncthreads();
    sh[t] += v;
    __syncthreads();
  }
  if (t < NBK) {
    int st = (t == 0) ? 0 : sh[t - 1];
    bucket_start[t] = st;
    bucket_cursor[t] = st;
  }
}

// phase 1c: multisplit scatter of (src,dst) pairs into bucket regions.
// Per-block reservation => each block's writes form ~168B contiguous runs
// owned by one CU (write amp ~1.5x instead of 16x).
__global__ __launch_bounds__(1024) void k_split(const int* __restrict__ src,
                                                const int* __restrict__ dst,
                                                int* __restrict__ bucket_cursor,
                                                int2* __restrict__ binned,
                                                int E, int NBK) {
  __shared__ int h[256];
  __shared__ int lcur[256];
  int t = threadIdx.x;
  if (t < 256) h[t] = 0;
  __syncthreads();
  int base = blockIdx.x * 4096;
  int s[4], d[4], b[4];
  bool val[4];
#pragma unroll
  for (int j = 0; j < 4; ++j) {
    int i = base + j * 1024 + t;
    val[j] = (i < E);
    if (val[j]) {
      s[j] = src[i];
      d[j] = dst[i];
      b[j] = d[j] >> DSHIFT;
      atomicAdd(&h[b[j]], 1);
    }
  }
  __syncthreads();
  if (t < NBK && h[t] > 0) lcur[t] = atomicAdd(&bucket_cursor[t], h[t]);
  __syncthreads();
#pragma unroll
  for (int j = 0; j < 4; ++j) {
    if (val[j]) {
      int pos = atomicAdd(&lcur[b[j]], 1);
      binned[pos] = make_int2(s[j], d[j]);
    }
  }
}

// phase 2: one block per bucket. LDS per-node count + scan -> rowptr/rowend/
// dis (coalesced), then LDS-cursor scatter of esrc into the bucket's
// contiguous region (single-CU write locality).
__global__ __launch_bounds__(1024) void k_bucket(const int2* __restrict__ binned,
                                                 const int* __restrict__ bucket_start,
                                                 const int* __restrict__ bucket_cnt,
                                                 int* __restrict__ rowptr,
                                                 int* __restrict__ rowend,
                                                 float* __restrict__ dis,
                                                 int* __restrict__ esrc, int N) {
  __shared__ int lcnt[DN];
  __shared__ int lscan[DN];
  int k = blockIdx.x;
  int t = threadIdx.x;
  int bstart = bucket_start[k];
  int cntk = bucket_cnt[k];
  int nbase = k << DSHIFT;
  if (t < DN) lcnt[t] = 0;
  __syncthreads();
  for (int i = t; i < cntk; i += 1024)
    atomicAdd(&lcnt[binned[bstart + i].y - nbase], 1);
  __syncthreads();
  if (t < DN) lscan[t] = lcnt[t];
  __syncthreads();
  for (int off = 1; off < DN; off <<= 1) {
    int v = (t < DN && t >= off) ? lscan[t - off] : 0;
    __syncthreads();
    if (t < DN) lscan[t] += v;
    __syncthreads();
  }
  if (t < DN) {
    int g = nbase + t;
    if (g < N) {
      int inc = lscan[t];
      int c = lcnt[t];
      rowptr[g] = bstart + inc - c;
      rowend[g] = bstart + inc;
      dis[g] = rsqrtf((float)(c + 1));
    }
    lcnt[t] = lscan[t] - lcnt[t];  // reuse as local exclusive cursor
  }
  __syncthreads();
  for (int i = t; i < cntk; i += 1024) {
    int2 e = binned[bstart + i];
    int slot = atomicAdd(&lcnt[e.y - nbase], 1);
    esrc[bstart + slot] = e.x;
  }
}

// out[nrows, COLS] (fp16) = dis[row] * (A[nrows, 128] (fp32) @ W[128, COLS]).
// Block = 64 rows x 64 cols; W-column tile in LDS (32KB -> 5 blocks/CU).
template <int COLS>
__global__ __launch_bounds__(256) void k_gemm(const float* __restrict__ A,
                                              const float* __restrict__ W,
                                              const float* __restrict__ dis,
                                              __half* __restrict__ out, int nrows) {
  __shared__ float Ws[128 * 64];
  int t = threadIdx.x;
  int cbase = blockIdx.y * 64;
  for (int i = t; i < 128 * 16; i += 256) {
    int k = i >> 4;
    int c = (i & 15) * 4;
    *(float4*)&Ws[k * 64 + c] = *(const float4*)&W[k * COLS + cbase + c];
  }
  __syncthreads();

  int tx = t & 15, ty = t >> 4;
  int row0 = blockIdx.x * 64 + ty * 4;
  int c0 = tx * 4;

  float acc[4][4];
#pragma unroll
  for (int r = 0; r < 4; ++r)
    acc[r][0] = acc[r][1] = acc[r][2] = acc[r][3] = 0.f;

  if (row0 + 4 <= nrows) {
    for (int k = 0; k < 128; k += 4) {
      float4 a0 = *(const float4*)&A[(size_t)(row0 + 0) * 128 + k];
      float4 a1 = *(const float4*)&A[(size_t)(row0 + 1) * 128 + k];
      float4 a2 = *(const float4*)&A[(size_t)(row0 + 2) * 128 + k];
      float4 a3 = *(const float4*)&A[(size_t)(row0 + 3) * 128 + k];
      float4 w0 = *(const float4*)&Ws[(k + 0) * 64 + c0];
      float4 w1 = *(const float4*)&Ws[(k + 1) * 64 + c0];
      float4 w2 = *(const float4*)&Ws[(k + 2) * 64 + c0];
      float4 w3 = *(const float4*)&Ws[(k + 3) * 64 + c0];
#define GEMM_FMA(r, a)                                  \
  acc[r][0] = fmaf(a.x, w0.x, acc[r][0]);               \
  acc[r][1] = fmaf(a.x, w0.y, acc[r][1]);               \
  acc[r][2] = fmaf(a.x, w0.z, acc[r][2]);               \
  acc[r][3] = fmaf(a.x, w0.w, acc[r][3]);               \
  acc[r][0] = fmaf(a.y, w1.x, acc[r][0]);               \
  acc[r][1] = fmaf(a.y, w1.y, acc[r][1]);               \
  acc[r][2] = fmaf(a.y, w1.z, acc[r][2]);               \
  acc[r][3] = fmaf(a.y, w1.w, acc[r][3]);               \
  acc[r][0] = fmaf(a.z, w2.x, acc[r][0]);               \
  acc[r][1] = fmaf(a.z, w2.y, acc[r][1]);               \
  acc[r][2] = fmaf(a.z, w2.z, acc[r][2]);               \
  acc[r][3] = fmaf(a.z, w2.w, acc[r][3]);               \
  acc[r][0] = fmaf(a.w, w3.x, acc[r][0]);               \
  acc[r][1] = fmaf(a.w, w3.y, acc[r][1]);               \
  acc[r][2] = fmaf(a.w, w3.z, acc[r][2]);               \
  acc[r][3] = fmaf(a.w, w3.w, acc[r][3]);
      GEMM_FMA(0, a0)
      GEMM_FMA(1, a1)
      GEMM_FMA(2, a2)
      GEMM_FMA(3, a3)
    }
#pragma unroll
    for (int r = 0; r < 4; ++r) {
      float dn = dis[row0 + r];
      union { __half2 h2[2]; float2 f2; } u;
      u.h2[0] = __floats2half2_rn(acc[r][0] * dn, acc[r][1] * dn);
      u.h2[1] = __floats2half2_rn(acc[r][2] * dn, acc[r][3] * dn);
      *(float2*)&out[(size_t)(row0 + r) * COLS + cbase + c0] = u.f2;
    }
  } else {
    for (int k = 0; k < 128; k += 4) {
      float4 w0 = *(const float4*)&Ws[(k + 0) * 64 + c0];
      float4 w1 = *(const float4*)&Ws[(k + 1) * 64 + c0];
      float4 w2 = *(const float4*)&Ws[(k + 2) * 64 + c0];
      float4 w3 = *(const float4*)&Ws[(k + 3) * 64 + c0];
      for (int r = 0; r < 4; ++r) {
        int row = row0 + r;
        if (row >= nrows) continue;
        float4 a = *(const float4*)&A[(size_t)row * 128 + k];
        GEMM_FMA(r, a)
      }
    }
#pragma unroll
    for (int r = 0; r < 4; ++r) {
      int row = row0 + r;
      if (row < nrows) {
        float dn = dis[row];
        union { __half2 h2[2]; float2 f2; } u;
        u.h2[0] = __floats2half2_rn(acc[r][0] * dn, acc[r][1] * dn);
        u.h2[1] = __floats2half2_rn(acc[r][2] * dn, acc[r][3] * dn);
        *(float2*)&out[(size_t)row * COLS + cbase + c0] = u.f2;
      }
    }
#undef GEMM_FMA
  }
}

// wave per node; COLS/8 lanes per edge-row (16B half8 loads), NG edge groups
// per wave, depth-2 pipeline. H pre-scaled by dis[src]; validity weight {0,1}.
template <int COLS>
__global__ __launch_bounds__(256) void k_agg(const __half* __restrict__ H,
                                             const int* __restrict__ rowptr,
                                             const int* __restrict__ rowend,
                                             const int* __restrict__ esrc,
                                             const float* __restrict__ dis,
                                             const float* __restrict__ bias,
                                             float* __restrict__ out, int n) {
  constexpr int LPE = COLS / 8;  // lanes per edge-row (16 or 8)
  constexpr int NG = 64 / LPE;   // edge groups per wave (4 or 8)
  int node = (blockIdx.x * 256 + threadIdx.x) >> 6;
  if (node >= n) return;
  int lane = threadIdx.x & 63;
  int group = lane / LPE;
  int c = (lane % LPE) * 8;

  float acc[8];
#pragma unroll
  for (int j = 0; j < 8; ++j) acc[j] = 0.f;

  int beg = rowptr[node], end = rowend[node];
  int e0 = beg + group;
  int e1 = e0 + NG;
  int s0 = 0, s1 = 0;
  float w0 = 0.f, w1 = 0.f;
  if (e0 < end) { s0 = esrc[e0]; w0 = 1.f; }
  if (e1 < end) { s1 = esrc[e1]; w1 = 1.f; }
  while (e0 < end) {
    float4 r0 = *(const float4*)&H[(size_t)s0 * COLS + c];
    float4 r1 = *(const float4*)&H[(size_t)s1 * COLS + c];
    int e2 = e0 + 2 * NG, e3 = e1 + 2 * NG;
    int s2 = 0, s3 = 0;
    float w2 = 0.f, w3 = 0.f;
    if (e2 < end) { s2 = esrc[e2]; w2 = 1.f; }
    if (e3 < end) { s3 = esrc[e3]; w3 = 1.f; }
    {
      union { float4 f4; __half2 h2[4]; } u;
      u.f4 = r0;
#pragma unroll
      for (int j = 0; j < 4; ++j) {
        float2 f = __half22float2(u.h2[j]);
        acc[2 * j + 0] = fmaf(f.x, w0, acc[2 * j + 0]);
        acc[2 * j + 1] = fmaf(f.y, w0, acc[2 * j + 1]);
      }
      u.f4 = r1;
#pragma unroll
      for (int j = 0; j < 4; ++j) {
        float2 f = __half22float2(u.h2[j]);
        acc[2 * j + 0] = fmaf(f.x, w1, acc[2 * j + 0]);
        acc[2 * j + 1] = fmaf(f.y, w1, acc[2 * j + 1]);
      }
    }
    e0 = e2; s0 = s2; w0 = w2;
    e1 = e3; s1 = s3; w1 = w3;
  }
#pragma unroll
  for (int m = LPE; m < 64; m <<= 1) {
#pragma unroll
    for (int j = 0; j < 8; ++j) acc[j] += __shfl_xor(acc[j], m, 64);
  }
  if (group == 0) {
    float dn = dis[node];
    union { float4 f4; __half2 h2[4]; } u;
    u.f4 = *(const float4*)&H[(size_t)node * COLS + c];
    float o[8];
#pragma unroll
    for (int j = 0; j < 4; ++j) {
      float2 f = __half22float2(u.h2[j]);
      o[2 * j + 0] = fmaxf(fmaf(acc[2 * j + 0] + f.x, dn, bias[c + 2 * j + 0]), 0.f);
      o[2 * j + 1] = fmaxf(fmaf(acc[2 * j + 1] + f.y, dn, bias[c + 2 * j + 1]), 0.f);
    }
    *(float4*)&out[(size_t)node * COLS + c] = make_float4(o[0], o[1], o[2], o[3]);
    *(float4*)&out[(size_t)node * COLS + c + 4] = make_float4(o[4], o[5], o[6], o[7]);
  }
}

// run-length pooling over sorted batch; 32 nodes per wave, lane = column
__global__ void k_pool(const float* __restrict__ H2, const int* __restrict__ batch,
                       float* __restrict__ psum, float* __restrict__ pcnt, int n) {
  int wv = (blockIdx.x * 256 + threadIdx.x) >> 6;
  int lane = threadIdx.x & 63;
  int start = wv * 32;
  if (start >= n) return;
  int end = min(start + 32, n);
  int curg = batch[start];
  float acc = 0.f;
  int cn = 0;
  for (int i = start; i < end; ++i) {
    int g = batch[i];
    if (g != curg) {
      atomicAdd(&psum[curg * 64 + lane], acc);
      if (lane == 0) atomicAdd(&pcnt[curg], (float)cn);
      acc = 0.f;
      cn = 0;
      curg = g;
    }
    acc += H2[(size_t)i * 64 + lane];
    ++cn;
  }
  atomicAdd(&psum[curg * 64 + lane], acc);
  if (lane == 0) atomicAdd(&pcnt[curg], (float)cn);
}

__global__ void k_final(const float* __restrict__ psum, const float* __restrict__ pcnt,
                        const float* __restrict__ lin_w, const float* __restrict__ lin_b,
                        float* __restrict__ out, int G) {
  int g = blockIdx.x * 64 + threadIdx.x;
  if (g >= G) return;
  float c = fmaxf(pcnt[g], 1.f);
  float s = 0.f;
  for (int i = 0; i < 64; ++i) s += psum[g * 64 + i] * lin_w[i];
  out[g] = s / c + lin_b[0];
}

extern "C" void kernel_launch(void* const* d_in, const int* in_sizes, int n_in,
                              void* d_out, int out_size, void* d_ws, size_t ws_size,
                              hipStream_t stream) {
  const float* x = (const float*)d_in[0];
  const int* edge = (const int*)d_in[1];
  const int* batch = (const int*)d_in[2];
  const float* W1 = (const float*)d_in[3];
  const float* b1 = (const float*)d_in[4];
  const float* W2 = (const float*)d_in[5];
  const float* b2 = (const float*)d_in[6];
  const float* lin_w = (const float*)d_in[7];
  const float* lin_b = (const float*)d_in[8];
  float* out = (float*)d_out;

  const int N = in_sizes[2];
  const int E = in_sizes[1] / 2;
  const int G = out_size;
  const int* esrc_in = edge;       // edge_index[0] = src
  const int* edst_in = edge + E;   // edge_index[1] = dst

  char* w = (char*)d_ws;
  size_t off = 0;
  auto take = [&](size_t bytes) {
    void* p = w + off;
    off += (bytes + 255) & ~(size_t)255;
    return p;
  };
  int* bucket_cnt = (int*)take(256 * 4);
  int* bucket_start = (int*)take(256 * 4);
  int* bucket_cursor = (int*)take(256 * 4);
  int* rowptr = (int*)take((size_t)N * 4);
  int* rowend = (int*)take((size_t)N * 4);
  float* dis = (float*)take((size_t)N * 4);
  int* esrc = (int*)take((size_t)E * 4);
  __half* XW = (__half*)take((size_t)N * 128 * 2);  // fp16; aliases binned
  float* H1 = (float*)take((size_t)N * 128 * 4);    // fp32; reused as H2 [N,64]
  float* psum = (float*)take((size_t)G * 64 * 4);
  float* pcnt = (float*)take((size_t)G * 4);
  int2* binned = (int2*)XW;  // E*8 bytes <= N*128*2 bytes; dead before gemm128
  (void)ws_size;
  (void)n_in;

  const int NBK = (N + DN - 1) / DN;       // 196 for N=100000 (must be <=256)
  const int PB = (E + 4095) / 4096;        // phase-1 blocks
  int ib = (max(G * 64, NBK) + 255) / 256;

  k_init<<<ib, 256, 0, stream>>>(bucket_cnt, psum, pcnt, NBK, G * 64, G);
  k_hist<<<PB, 1024, 0, stream>>>(edst_in, bucket_cnt, E, NBK);
  k_bscan<<<1, 256, 0, stream>>>(bucket_cnt, bucket_start, bucket_cursor, NBK);
  k_split<<<PB, 1024, 0, stream>>>(esrc_in, edst_in, bucket_cursor, binned, E, NBK);
  k_bucket<<<NBK, 1024, 0, stream>>>(binned, bucket_start, bucket_cnt,
                                     rowptr, rowend, dis, esrc, N);

  int gb = (N + 63) / 64;
  int ab = (int)(((size_t)N * 64 + 255) / 256);

  // layer 1: XW = fp16(dis * (x@W1)); H1 = relu(dis*(selfrow+sum) + b1) fp32
  k_gemm<128><<<dim3(gb, 2), 256, 0, stream>>>(x, W1, dis, XW, N);
  k_agg<128><<<ab, 256, 0, stream>>>(XW, rowptr, rowend, esrc, dis, b1, H1, N);

  // layer 2: XW[:, :64] = fp16(dis * (H1@W2)); H2 (into H1 buffer)
  k_gemm<64><<<dim3(gb, 1), 256, 0, stream>>>(H1, W2, dis, XW, N);
  k_agg<64><<<ab, 256, 0, stream>>>(XW, rowptr, rowend, esrc, dis, b2, H1, N);

  // mean-pool + linear head
  int pb = (int)((((size_t)(N + 31) / 32) * 64 + 255) / 256);
  k_pool<<<pb, 256, 0, stream>>>(H1, batch, psum, pcnt, N);
  k_final<<<1, 64, 0, stream>>>(psum, pcnt, lin_w, lin_b, out, G);
}

// Round 9
// 332.898 us; speedup vs baseline: 1.5722x; 1.1108x over previous
//
#include <hip/hip_runtime.h>
#include <hip/hip_fp16.h>

// ---------------------------------------------------------------------------
// GCN forward: 2x GCNConv(relu) + global_mean_pool + linear
// CSR via two-level bucket multisplit (R7). GEMMs are fp16 MFMA with LDS-
// staged A-tile + W^T (R8/R9), dis[row] folded into fp16 epilogue. Agg is an
// unweighted fp16 gather-sum scaled by dis[dst]:
//   out[d] = relu(dis[d]*(XW'[d] + sum XW'[src]) + b)
// R1: multi-block scan. R2: multi-edge-group agg. R3: fp16 gather operand.
// R4: 64x64 GEMM tiles. R5: enorm eliminated. R6: FAILED (locality, not
// bytes). R7: bucket multisplit build (523->370us). R8: FAILED - layer2
// instantiated with K=64 but H1 is [N,128] (half-length dot product).
// R9: k_gemm<64,128> for layer 2 (GEMM K is the inner dim, not COLS).
// ---------------------------------------------------------------------------

#define DN 512      // dst nodes per bucket
#define DSHIFT 9    // log2(DN)

typedef _Float16 half8 __attribute__((ext_vector_type(8)));
typedef float f32x4 __attribute__((ext_vector_type(4)));

__global__ void k_init(int* __restrict__ bucket_cnt, float* __restrict__ psum,
                       float* __restrict__ pcnt, int NBK, int psumN, int G) {
  int i = blockIdx.x * 256 + threadIdx.x;
  if (i < NBK) bucket_cnt[i] = 0;
  if (i < psumN) psum[i] = 0.f;
  if (i < G) pcnt[i] = 0.f;
}

// phase 1a: per-block LDS histogram of dst buckets -> global bucket_cnt
__global__ __launch_bounds__(1024) void k_hist(const int* __restrict__ dst,
                                               int* __restrict__ bucket_cnt,
                                               int E, int NBK) {
  __shared__ int h[256];
  int t = threadIdx.x;
  if (t < 256) h[t] = 0;
  __syncthreads();
  int base = blockIdx.x * 4096;
#pragma unroll
  for (int j = 0; j < 4; ++j) {
    int i = base + j * 1024 + t;
    if (i < E) atomicAdd(&h[dst[i] >> DSHIFT], 1);
  }
  __syncthreads();
  if (t < NBK && h[t] > 0) atomicAdd(&bucket_cnt[t], h[t]);
}

// phase 1b: scan bucket counts -> bucket_start, bucket_cursor (NBK <= 256)
__global__ __launch_bounds__(256) void k_bscan(const int* __restrict__ bucket_cnt,
                                               int* __restrict__ bucket_start,
                                               int* __restrict__ bucket_cursor,
                                               int NBK) {
  __shared__ int sh[256];
  int t = threadIdx.x;
  sh[t] = (t < NBK) ? bucket_cnt[t] : 0;
  __syncthreads();
  for (int off = 1; off < 256; off <<= 1) {
    int v = (t >= off) ? sh[t - off] : 0;
    __syncthreads();
    sh[t] += v;
    __syncthreads();
  }
  if (t < NBK) {
    int st = (t == 0) ? 0 : sh[t - 1];
    bucket_start[t] = st;
    bucket_cursor[t] = st;
  }
}

// phase 1c: multisplit scatter of (src,dst) pairs into bucket regions.
__global__ __launch_bounds__(1024) void k_split(const int* __restrict__ src,
                                                const int* __restrict__ dst,
                                                int* __restrict__ bucket_cursor,
                                                int2* __restrict__ binned,
                                                int E, int NBK) {
  __shared__ int h[256];
  __shared__ int lcur[256];
  int t = threadIdx.x;
  if (t < 256) h[t] = 0;
  __syncthreads();
  int base = blockIdx.x * 4096;
  int s[4], d[4], b[4];
  bool val[4];
#pragma unroll
  for (int j = 0; j < 4; ++j) {
    int i = base + j * 1024 + t;
    val[j] = (i < E);
    if (val[j]) {
      s[j] = src[i];
      d[j] = dst[i];
      b[j] = d[j] >> DSHIFT;
      atomicAdd(&h[b[j]], 1);
    }
  }
  __syncthreads();
  if (t < NBK && h[t] > 0) lcur[t] = atomicAdd(&bucket_cursor[t], h[t]);
  __syncthreads();
#pragma unroll
  for (int j = 0; j < 4; ++j) {
    if (val[j]) {
      int pos = atomicAdd(&lcur[b[j]], 1);
      binned[pos] = make_int2(s[j], d[j]);
    }
  }
}

// phase 2: one block per bucket. LDS per-node count + scan -> rowptr/rowend/
// dis, then LDS-cursor scatter of esrc into contiguous bucket region.
__global__ __launch_bounds__(1024) void k_bucket(const int2* __restrict__ binned,
                                                 const int* __restrict__ bucket_start,
                                                 const int* __restrict__ bucket_cnt,
                                                 int* __restrict__ rowptr,
                                                 int* __restrict__ rowend,
                                                 float* __restrict__ dis,
                                                 int* __restrict__ esrc, int N) {
  __shared__ int lcnt[DN];
  __shared__ int lscan[DN];
  int k = blockIdx.x;
  int t = threadIdx.x;
  int bstart = bucket_start[k];
  int cntk = bucket_cnt[k];
  int nbase = k << DSHIFT;
  if (t < DN) lcnt[t] = 0;
  __syncthreads();
  for (int i = t; i < cntk; i += 1024)
    atomicAdd(&lcnt[binned[bstart + i].y - nbase], 1);
  __syncthreads();
  if (t < DN) lscan[t] = lcnt[t];
  __syncthreads();
  for (int off = 1; off < DN; off <<= 1) {
    int v = (t < DN && t >= off) ? lscan[t - off] : 0;
    __syncthreads();
    if (t < DN) lscan[t] += v;
    __syncthreads();
  }
  if (t < DN) {
    int g = nbase + t;
    if (g < N) {
      int inc = lscan[t];
      int c = lcnt[t];
      rowptr[g] = bstart + inc - c;
      rowend[g] = bstart + inc;
      dis[g] = rsqrtf((float)(c + 1));
    }
    lcnt[t] = lscan[t] - lcnt[t];  // reuse as local exclusive cursor
  }
  __syncthreads();
  for (int i = t; i < cntk; i += 1024) {
    int2 e = binned[bstart + i];
    int slot = atomicAdd(&lcnt[e.y - nbase], 1);
    esrc[bstart + slot] = e.x;
  }
}

// out[nrows, COLS] (fp16) = dis[row] * (A[nrows, K] (fp32) @ W[K, COLS]).
// MFMA 16x16x32_f16. Block = 64 rows x 64 cols, 4 waves; A-tile and W^T
// staged fp16 in LDS with +8-half pad. Verified layouts (m89/m120):
// A[m=lane&15][k=quad*8+j]; B[k=quad*8+j][n=lane&15]; D col=lane&15,
// row=quad*4+reg. NOTE: K is the INNER dim (A width), independent of COLS.
template <int COLS, int K>
__global__ __launch_bounds__(256) void k_gemm(const float* __restrict__ A,
                                              const float* __restrict__ W,
                                              const float* __restrict__ dis,
                                              __half* __restrict__ out, int nrows) {
  constexpr int KP = K + 8;  // padded LDS stride (halves)
  __shared__ _Float16 As[64 * KP];
  __shared__ _Float16 Wt[64 * KP];
  int t = threadIdx.x;
  int row0 = blockIdx.x * 64;
  int cbase = blockIdx.y * 64;

  // stage W^T (fp16): thread reads W[k][cbase + c4..c4+4) float4
  {
    int c4 = (t & 15) * 4;
    for (int k = t >> 4; k < K; k += 16) {
      float4 wv = *(const float4*)&W[(size_t)k * COLS + cbase + c4];
      Wt[(c4 + 0) * KP + k] = (_Float16)wv.x;
      Wt[(c4 + 1) * KP + k] = (_Float16)wv.y;
      Wt[(c4 + 2) * KP + k] = (_Float16)wv.z;
      Wt[(c4 + 3) * KP + k] = (_Float16)wv.w;
    }
  }
  // stage A tile (fp16), zero-fill OOB rows
  {
    constexpr int F4 = K / 4;  // float4 per row
    for (int id = t; id < 64 * F4; id += 256) {
      int r = id / F4, kq = (id % F4) * 4;
      int grow = row0 + r;
      float4 av = (grow < nrows) ? *(const float4*)&A[(size_t)grow * K + kq]
                                 : make_float4(0.f, 0.f, 0.f, 0.f);
      _Float16* dst = &As[r * KP + kq];
      dst[0] = (_Float16)av.x;
      dst[1] = (_Float16)av.y;
      dst[2] = (_Float16)av.z;
      dst[3] = (_Float16)av.w;
    }
  }
  __syncthreads();

  int wave = t >> 6, lane = t & 63;
  int m = lane & 15;     // A row / B col / D col within 16-tile
  int quad = lane >> 4;  // k-group for A/B; row-group for D

  f32x4 acc[4];
#pragma unroll
  for (int ct = 0; ct < 4; ++ct) acc[ct] = (f32x4){0.f, 0.f, 0.f, 0.f};

  const _Float16* arow = &As[(wave * 16 + m) * KP + quad * 8];
#pragma unroll
  for (int ks = 0; ks < K; ks += 32) {
    half8 af = *(const half8*)&arow[ks];
#pragma unroll
    for (int ct = 0; ct < 4; ++ct) {
      half8 bf = *(const half8*)&Wt[(ct * 16 + m) * KP + quad * 8 + ks];
      acc[ct] = __builtin_amdgcn_mfma_f32_16x16x32_f16(af, bf, acc[ct], 0, 0, 0);
    }
  }

  // epilogue: D row = quad*4+j, col = ct*16+m; scale by dis[row], store fp16
#pragma unroll
  for (int j = 0; j < 4; ++j) {
    int gr = row0 + wave * 16 + quad * 4 + j;
    if (gr < nrows) {
      float dn = dis[gr];
#pragma unroll
      for (int ct = 0; ct < 4; ++ct)
        out[(size_t)gr * COLS + cbase + ct * 16 + m] =
            __float2half_rn(acc[ct][j] * dn);
    }
  }
}

// wave per node; COLS/8 lanes per edge-row (16B half8 loads), NG edge groups
// per wave, depth-2 pipeline. H pre-scaled by dis[src]; validity weight {0,1}.
template <int COLS>
__global__ __launch_bounds__(256) void k_agg(const __half* __restrict__ H,
                                             const int* __restrict__ rowptr,
                                             const int* __restrict__ rowend,
                                             const int* __restrict__ esrc,
                                             const float* __restrict__ dis,
                                             const float* __restrict__ bias,
                                             float* __restrict__ out, int n) {
  constexpr int LPE = COLS / 8;  // lanes per edge-row (16 or 8)
  constexpr int NG = 64 / LPE;   // edge groups per wave (4 or 8)
  int node = (blockIdx.x * 256 + threadIdx.x) >> 6;
  if (node >= n) return;
  int lane = threadIdx.x & 63;
  int group = lane / LPE;
  int c = (lane % LPE) * 8;

  float acc[8];
#pragma unroll
  for (int j = 0; j < 8; ++j) acc[j] = 0.f;

  int beg = rowptr[node], end = rowend[node];
  int e0 = beg + group;
  int e1 = e0 + NG;
  int s0 = 0, s1 = 0;
  float w0 = 0.f, w1 = 0.f;
  if (e0 < end) { s0 = esrc[e0]; w0 = 1.f; }
  if (e1 < end) { s1 = esrc[e1]; w1 = 1.f; }
  while (e0 < end) {
    float4 r0 = *(const float4*)&H[(size_t)s0 * COLS + c];
    float4 r1 = *(const float4*)&H[(size_t)s1 * COLS + c];
    int e2 = e0 + 2 * NG, e3 = e1 + 2 * NG;
    int s2 = 0, s3 = 0;
    float w2 = 0.f, w3 = 0.f;
    if (e2 < end) { s2 = esrc[e2]; w2 = 1.f; }
    if (e3 < end) { s3 = esrc[e3]; w3 = 1.f; }
    {
      union { float4 f4; __half2 h2[4]; } u;
      u.f4 = r0;
#pragma unroll
      for (int j = 0; j < 4; ++j) {
        float2 f = __half22float2(u.h2[j]);
        acc[2 * j + 0] = fmaf(f.x, w0, acc[2 * j + 0]);
        acc[2 * j + 1] = fmaf(f.y, w0, acc[2 * j + 1]);
      }
      u.f4 = r1;
#pragma unroll
      for (int j = 0; j < 4; ++j) {
        float2 f = __half22float2(u.h2[j]);
        acc[2 * j + 0] = fmaf(f.x, w1, acc[2 * j + 0]);
        acc[2 * j + 1] = fmaf(f.y, w1, acc[2 * j + 1]);
      }
    }
    e0 = e2; s0 = s2; w0 = w2;
    e1 = e3; s1 = s3; w1 = w3;
  }
#pragma unroll
  for (int m = LPE; m < 64; m <<= 1) {
#pragma unroll
    for (int j = 0; j < 8; ++j) acc[j] += __shfl_xor(acc[j], m, 64);
  }
  if (group == 0) {
    float dn = dis[node];
    union { float4 f4; __half2 h2[4]; } u;
    u.f4 = *(const float4*)&H[(size_t)node * COLS + c];
    float o[8];
#pragma unroll
    for (int j = 0; j < 4; ++j) {
      float2 f = __half22float2(u.h2[j]);
      o[2 * j + 0] = fmaxf(fmaf(acc[2 * j + 0] + f.x, dn, bias[c + 2 * j + 0]), 0.f);
      o[2 * j + 1] = fmaxf(fmaf(acc[2 * j + 1] + f.y, dn, bias[c + 2 * j + 1]), 0.f);
    }
    *(float4*)&out[(size_t)node * COLS + c] = make_float4(o[0], o[1], o[2], o[3]);
    *(float4*)&out[(size_t)node * COLS + c + 4] = make_float4(o[4], o[5], o[6], o[7]);
  }
}

// run-length pooling over sorted batch; 32 nodes per wave, lane = column
__global__ void k_pool(const float* __restrict__ H2, const int* __restrict__ batch,
                       float* __restrict__ psum, float* __restrict__ pcnt, int n) {
  int wv = (blockIdx.x * 256 + threadIdx.x) >> 6;
  int lane = threadIdx.x & 63;
  int start = wv * 32;
  if (start >= n) return;
  int end = min(start + 32, n);
  int curg = batch[start];
  float acc = 0.f;
  int cn = 0;
  for (int i = start; i < end; ++i) {
    int g = batch[i];
    if (g != curg) {
      atomicAdd(&psum[curg * 64 + lane], acc);
      if (lane == 0) atomicAdd(&pcnt[curg], (float)cn);
      acc = 0.f;
      cn = 0;
      curg = g;
    }
    acc += H2[(size_t)i * 64 + lane];
    ++cn;
  }
  atomicAdd(&psum[curg * 64 + lane], acc);
  if (lane == 0) atomicAdd(&pcnt[curg], (float)cn);
}

__global__ void k_final(const float* __restrict__ psum, const float* __restrict__ pcnt,
                        const float* __restrict__ lin_w, const float* __restrict__ lin_b,
                        float* __restrict__ out, int G) {
  int g = blockIdx.x * 64 + threadIdx.x;
  if (g >= G) return;
  float c = fmaxf(pcnt[g], 1.f);
  float s = 0.f;
  for (int i = 0; i < 64; ++i) s += psum[g * 64 + i] * lin_w[i];
  out[g] = s / c + lin_b[0];
}

extern "C" void kernel_launch(void* const* d_in, const int* in_sizes, int n_in,
                              void* d_out, int out_size, void* d_ws, size_t ws_size,
                              hipStream_t stream) {
  const float* x = (const float*)d_in[0];
  const int* edge = (const int*)d_in[1];
  const int* batch = (const int*)d_in[2];
  const float* W1 = (const float*)d_in[3];
  const float* b1 = (const float*)d_in[4];
  const float* W2 = (const float*)d_in[5];
  const float* b2 = (const float*)d_in[6];
  const float* lin_w = (const float*)d_in[7];
  const float* lin_b = (const float*)d_in[8];
  float* out = (float*)d_out;

  const int N = in_sizes[2];
  const int E = in_sizes[1] / 2;
  const int G = out_size;
  const int* esrc_in = edge;       // edge_index[0] = src
  const int* edst_in = edge + E;   // edge_index[1] = dst

  char* w = (char*)d_ws;
  size_t off = 0;
  auto take = [&](size_t bytes) {
    void* p = w + off;
    off += (bytes + 255) & ~(size_t)255;
    return p;
  };
  int* bucket_cnt = (int*)take(256 * 4);
  int* bucket_start = (int*)take(256 * 4);
  int* bucket_cursor = (int*)take(256 * 4);
  int* rowptr = (int*)take((size_t)N * 4);
  int* rowend = (int*)take((size_t)N * 4);
  float* dis = (float*)take((size_t)N * 4);
  int* esrc = (int*)take((size_t)E * 4);
  __half* XW = (__half*)take((size_t)N * 128 * 2);  // fp16; aliases binned
  float* H1 = (float*)take((size_t)N * 128 * 4);    // fp32; reused as H2 [N,64]
  float* psum = (float*)take((size_t)G * 64 * 4);
  float* pcnt = (float*)take((size_t)G * 4);
  int2* binned = (int2*)XW;  // E*8 bytes <= N*128*2 bytes; dead before gemm128
  (void)ws_size;
  (void)n_in;

  const int NBK = (N + DN - 1) / DN;       // 196 for N=100000 (must be <=256)
  const int PB = (E + 4095) / 4096;        // phase-1 blocks
  int ib = (max(G * 64, NBK) + 255) / 256;

  k_init<<<ib, 256, 0, stream>>>(bucket_cnt, psum, pcnt, NBK, G * 64, G);
  k_hist<<<PB, 1024, 0, stream>>>(edst_in, bucket_cnt, E, NBK);
  k_bscan<<<1, 256, 0, stream>>>(bucket_cnt, bucket_start, bucket_cursor, NBK);
  k_split<<<PB, 1024, 0, stream>>>(esrc_in, edst_in, bucket_cursor, binned, E, NBK);
  k_bucket<<<NBK, 1024, 0, stream>>>(binned, bucket_start, bucket_cnt,
                                     rowptr, rowend, dis, esrc, N);

  int gb = (N + 63) / 64;
  int ab = (int)(((size_t)N * 64 + 255) / 256);

  // layer 1: XW = fp16(dis * (x@W1)), K=128; H1 = relu(dis*(self+sum)+b1)
  k_gemm<128, 128><<<dim3(gb, 2), 256, 0, stream>>>(x, W1, dis, XW, N);
  k_agg<128><<<ab, 256, 0, stream>>>(XW, rowptr, rowend, esrc, dis, b1, H1, N);

  // layer 2: XW[:, :64] = fp16(dis * (H1@W2)), K=128 (H1 is [N,128])
  k_gemm<64, 128><<<dim3(gb, 1), 256, 0, stream>>>(H1, W2, dis, XW, N);
  k_agg<64><<<ab, 256, 0, stream>>>(XW, rowptr, rowend, esrc, dis, b2, H1, N);

  // mean-pool + linear head
  int pb = (int)((((size_t)(N + 31) / 32) * 64 + 255) / 256);
  k_pool<<<pb, 256, 0, stream>>>(H1, batch, psum, pcnt, N);
  k_final<<<1, 64, 0, stream>>>(psum, pcnt, lin_w, lin_b, out, G);
}

// Round 10
// 317.021 us; speedup vs baseline: 1.6509x; 1.0501x over previous
//
#include <hip/hip_runtime.h>
#include <hip/hip_fp16.h>

// ---------------------------------------------------------------------------
// GCN forward: 2x GCNConv(relu) + global_mean_pool + linear
// CSR via two-level bucket multisplit (R7), binned edges packed to int32
// (src<<9 | local_dst, R10). GEMMs are fp16 MFMA with LDS-staged A + W^T,
// dis[row] folded into fp16 epilogue. All intermediate node features fp16
// (R10): agg writes fp16, layer-2 GEMM stages fp16 directly, pool reads fp16.
//   out[d] = relu(dis[d]*(XW'[d] + sum XW'[src]) + b)
// R1 scan fix. R2 multi-edge-group agg. R3 fp16 gather operand. R4 64x64
// GEMM tiles. R5 enorm eliminated. R6 FAILED (locality not bytes).
// R7 bucket multisplit (523->370). R8 FAILED K=64 layer2. R9 MFMA GEMM
// (370->333). R10: fp16 H1/H2 + packed binned (write/read byte cuts).
// ---------------------------------------------------------------------------

#define DN 512      // dst nodes per bucket
#define DSHIFT 9    // log2(DN)

typedef _Float16 half8 __attribute__((ext_vector_type(8)));
typedef float f32x4 __attribute__((ext_vector_type(4)));

__global__ void k_init(int* __restrict__ bucket_cnt, float* __restrict__ psum,
                       float* __restrict__ pcnt, int NBK, int psumN, int G) {
  int i = blockIdx.x * 256 + threadIdx.x;
  if (i < NBK) bucket_cnt[i] = 0;
  if (i < psumN) psum[i] = 0.f;
  if (i < G) pcnt[i] = 0.f;
}

// phase 1a: per-block LDS histogram of dst buckets -> global bucket_cnt
__global__ __launch_bounds__(1024) void k_hist(const int* __restrict__ dst,
                                               int* __restrict__ bucket_cnt,
                                               int E, int NBK) {
  __shared__ int h[256];
  int t = threadIdx.x;
  if (t < 256) h[t] = 0;
  __syncthreads();
  int base = blockIdx.x * 4096;
#pragma unroll
  for (int j = 0; j < 4; ++j) {
    int i = base + j * 1024 + t;
    if (i < E) atomicAdd(&h[dst[i] >> DSHIFT], 1);
  }
  __syncthreads();
  if (t < NBK && h[t] > 0) atomicAdd(&bucket_cnt[t], h[t]);
}

// phase 1b: scan bucket counts -> bucket_start, bucket_cursor (NBK <= 256)
__global__ __launch_bounds__(256) void k_bscan(const int* __restrict__ bucket_cnt,
                                               int* __restrict__ bucket_start,
                                               int* __restrict__ bucket_cursor,
                                               int NBK) {
  __shared__ int sh[256];
  int t = threadIdx.x;
  sh[t] = (t < NBK) ? bucket_cnt[t] : 0;
  __syncthreads();
  for (int off = 1; off < 256; off <<= 1) {
    int v = (t >= off) ? sh[t - off] : 0;
    __syncthreads();
    sh[t] += v;
    __syncthreads();
  }
  if (t < NBK) {
    int st = (t == 0) ? 0 : sh[t - 1];
    bucket_start[t] = st;
    bucket_cursor[t] = st;
  }
}

// phase 1c: multisplit scatter of packed (src<<9 | local_dst) into buckets.
__global__ __launch_bounds__(1024) void k_split(const int* __restrict__ src,
                                                const int* __restrict__ dst,
                                                int* __restrict__ bucket_cursor,
                                                int* __restrict__ binned,
                                                int E, int NBK) {
  __shared__ int h[256];
  __shared__ int lcur[256];
  int t = threadIdx.x;
  if (t < 256) h[t] = 0;
  __syncthreads();
  int base = blockIdx.x * 4096;
  int pk[4], b[4];
  bool val[4];
#pragma unroll
  for (int j = 0; j < 4; ++j) {
    int i = base + j * 1024 + t;
    val[j] = (i < E);
    if (val[j]) {
      int s = src[i], d = dst[i];
      b[j] = d >> DSHIFT;
      pk[j] = (s << DSHIFT) | (d & (DN - 1));
      atomicAdd(&h[b[j]], 1);
    }
  }
  __syncthreads();
  if (t < NBK && h[t] > 0) lcur[t] = atomicAdd(&bucket_cursor[t], h[t]);
  __syncthreads();
#pragma unroll
  for (int j = 0; j < 4; ++j) {
    if (val[j]) {
      int pos = atomicAdd(&lcur[b[j]], 1);
      binned[pos] = pk[j];
    }
  }
}

// phase 2: one block per bucket. LDS per-node count + scan -> rowptr/rowend/
// dis, then LDS-cursor scatter of esrc into contiguous bucket region.
__global__ __launch_bounds__(1024) void k_bucket(const int* __restrict__ binned,
                                                 const int* __restrict__ bucket_start,
                                                 const int* __restrict__ bucket_cnt,
                                                 int* __restrict__ rowptr,
                                                 int* __restrict__ rowend,
                                                 float* __restrict__ dis,
                                                 int* __restrict__ esrc, int N) {
  __shared__ int lcnt[DN];
  __shared__ int lscan[DN];
  int k = blockIdx.x;
  int t = threadIdx.x;
  int bstart = bucket_start[k];
  int cntk = bucket_cnt[k];
  int nbase = k << DSHIFT;
  if (t < DN) lcnt[t] = 0;
  __syncthreads();
  for (int i = t; i < cntk; i += 1024)
    atomicAdd(&lcnt[binned[bstart + i] & (DN - 1)], 1);
  __syncthreads();
  if (t < DN) lscan[t] = lcnt[t];
  __syncthreads();
  for (int off = 1; off < DN; off <<= 1) {
    int v = (t < DN && t >= off) ? lscan[t - off] : 0;
    __syncthreads();
    if (t < DN) lscan[t] += v;
    __syncthreads();
  }
  if (t < DN) {
    int g = nbase + t;
    if (g < N) {
      int inc = lscan[t];
      int c = lcnt[t];
      rowptr[g] = bstart + inc - c;
      rowend[g] = bstart + inc;
      dis[g] = rsqrtf((float)(c + 1));
    }
    lcnt[t] = lscan[t] - lcnt[t];  // reuse as local exclusive cursor
  }
  __syncthreads();
  for (int i = t; i < cntk; i += 1024) {
    int p = binned[bstart + i];
    int slot = atomicAdd(&lcnt[p & (DN - 1)], 1);
    esrc[bstart + slot] = (unsigned)p >> DSHIFT;
  }
}

// out[nrows, COLS] (fp16) = dis[row] * (A[nrows, K] @ W[K, COLS] fp32).
// MFMA 16x16x32_f16. Block = 64 rows x 64 cols, 4 waves; A-tile and W^T
// staged fp16 in LDS (+8-half pad). AT = float (cvt on stage) or _Float16
// (direct half8 copy). Verified layouts (m89/m120): A[m=lane&15][k=quad*8+j];
// B[k=quad*8+j][n=lane&15]; D col=lane&15, row=quad*4+reg.
template <int COLS, int K, typename AT>
__global__ __launch_bounds__(256) void k_gemm(const AT* __restrict__ A,
                                              const float* __restrict__ W,
                                              const float* __restrict__ dis,
                                              __half* __restrict__ out, int nrows) {
  constexpr int KP = K + 8;  // padded LDS stride (halves)
  __shared__ _Float16 As[64 * KP];
  __shared__ _Float16 Wt[64 * KP];
  int t = threadIdx.x;
  int row0 = blockIdx.x * 64;
  int cbase = blockIdx.y * 64;

  // stage W^T (fp16)
  {
    int c4 = (t & 15) * 4;
    for (int k = t >> 4; k < K; k += 16) {
      float4 wv = *(const float4*)&W[(size_t)k * COLS + cbase + c4];
      Wt[(c4 + 0) * KP + k] = (_Float16)wv.x;
      Wt[(c4 + 1) * KP + k] = (_Float16)wv.y;
      Wt[(c4 + 2) * KP + k] = (_Float16)wv.z;
      Wt[(c4 + 3) * KP + k] = (_Float16)wv.w;
    }
  }
  // stage A tile (fp16), zero-fill OOB rows
  if constexpr (sizeof(AT) == 4) {
    constexpr int F4 = K / 4;
    for (int id = t; id < 64 * F4; id += 256) {
      int r = id / F4, kq = (id % F4) * 4;
      int grow = row0 + r;
      float4 av = (grow < nrows) ? *(const float4*)&A[(size_t)grow * K + kq]
                                 : make_float4(0.f, 0.f, 0.f, 0.f);
      _Float16* dst = &As[r * KP + kq];
      dst[0] = (_Float16)av.x;
      dst[1] = (_Float16)av.y;
      dst[2] = (_Float16)av.z;
      dst[3] = (_Float16)av.w;
    }
  } else {
    constexpr int H8 = K / 8;
    for (int id = t; id < 64 * H8; id += 256) {
      int r = id / H8, kq = (id % H8) * 8;
      int grow = row0 + r;
      half8 av = (grow < nrows)
                     ? *(const half8*)&A[(size_t)grow * K + kq]
                     : (half8){0, 0, 0, 0, 0, 0, 0, 0};
      *(half8*)&As[r * KP + kq] = av;
    }
  }
  __syncthreads();

  int wave = t >> 6, lane = t & 63;
  int m = lane & 15;     // A row / B col / D col within 16-tile
  int quad = lane >> 4;  // k-group for A/B; row-group for D

  f32x4 acc[4];
#pragma unroll
  for (int ct = 0; ct < 4; ++ct) acc[ct] = (f32x4){0.f, 0.f, 0.f, 0.f};

  const _Float16* arow = &As[(wave * 16 + m) * KP + quad * 8];
#pragma unroll
  for (int ks = 0; ks < K; ks += 32) {
    half8 af = *(const half8*)&arow[ks];
#pragma unroll
    for (int ct = 0; ct < 4; ++ct) {
      half8 bf = *(const half8*)&Wt[(ct * 16 + m) * KP + quad * 8 + ks];
      acc[ct] = __builtin_amdgcn_mfma_f32_16x16x32_f16(af, bf, acc[ct], 0, 0, 0);
    }
  }

  // epilogue: D row = quad*4+j, col = ct*16+m; scale by dis[row], store fp16
#pragma unroll
  for (int j = 0; j < 4; ++j) {
    int gr = row0 + wave * 16 + quad * 4 + j;
    if (gr < nrows) {
      float dn = dis[gr];
#pragma unroll
      for (int ct = 0; ct < 4; ++ct)
        out[(size_t)gr * COLS + cbase + ct * 16 + m] =
            __float2half_rn(acc[ct][j] * dn);
    }
  }
}

// wave per node; COLS/8 lanes per edge-row (16B half8 loads), NG edge groups
// per wave, depth-2 pipeline. H pre-scaled by dis[src]; validity weight {0,1}.
// fp32 accumulate, fp16 output (consumers restage/accumulate anyway).
template <int COLS>
__global__ __launch_bounds__(256) void k_agg(const __half* __restrict__ H,
                                             const int* __restrict__ rowptr,
                                             const int* __restrict__ rowend,
                                             const int* __restrict__ esrc,
                                             const float* __restrict__ dis,
                                             const float* __restrict__ bias,
                                             __half* __restrict__ out, int n) {
  constexpr int LPE = COLS / 8;  // lanes per edge-row (16 or 8)
  constexpr int NG = 64 / LPE;   // edge groups per wave (4 or 8)
  int node = (blockIdx.x * 256 + threadIdx.x) >> 6;
  if (node >= n) return;
  int lane = threadIdx.x & 63;
  int group = lane / LPE;
  int c = (lane % LPE) * 8;

  float acc[8];
#pragma unroll
  for (int j = 0; j < 8; ++j) acc[j] = 0.f;

  int beg = rowptr[node], end = rowend[node];
  int e0 = beg + group;
  int e1 = e0 + NG;
  int s0 = 0, s1 = 0;
  float w0 = 0.f, w1 = 0.f;
  if (e0 < end) { s0 = esrc[e0]; w0 = 1.f; }
  if (e1 < end) { s1 = esrc[e1]; w1 = 1.f; }
  while (e0 < end) {
    float4 r0 = *(const float4*)&H[(size_t)s0 * COLS + c];
    float4 r1 = *(const float4*)&H[(size_t)s1 * COLS + c];
    int e2 = e0 + 2 * NG, e3 = e1 + 2 * NG;
    int s2 = 0, s3 = 0;
    float w2 = 0.f, w3 = 0.f;
    if (e2 < end) { s2 = esrc[e2]; w2 = 1.f; }
    if (e3 < end) { s3 = esrc[e3]; w3 = 1.f; }
    {
      union { float4 f4; __half2 h2[4]; } u;
      u.f4 = r0;
#pragma unroll
      for (int j = 0; j < 4; ++j) {
        float2 f = __half22float2(u.h2[j]);
        acc[2 * j + 0] = fmaf(f.x, w0, acc[2 * j + 0]);
        acc[2 * j + 1] = fmaf(f.y, w0, acc[2 * j + 1]);
      }
      u.f4 = r1;
#pragma unroll
      for (int j = 0; j < 4; ++j) {
        float2 f = __half22float2(u.h2[j]);
        acc[2 * j + 0] = fmaf(f.x, w1, acc[2 * j + 0]);
        acc[2 * j + 1] = fmaf(f.y, w1, acc[2 * j + 1]);
      }
    }
    e0 = e2; s0 = s2; w0 = w2;
    e1 = e3; s1 = s3; w1 = w3;
  }
#pragma unroll
  for (int m = LPE; m < 64; m <<= 1) {
#pragma unroll
    for (int j = 0; j < 8; ++j) acc[j] += __shfl_xor(acc[j], m, 64);
  }
  if (group == 0) {
    float dn = dis[node];
    union { float4 f4; __half2 h2[4]; } u;
    u.f4 = *(const float4*)&H[(size_t)node * COLS + c];
    union { __half2 h2[4]; float4 f4; } o;
#pragma unroll
    for (int j = 0; j < 4; ++j) {
      float2 f = __half22float2(u.h2[j]);
      float ox = fmaxf(fmaf(acc[2 * j + 0] + f.x, dn, bias[c + 2 * j + 0]), 0.f);
      float oy = fmaxf(fmaf(acc[2 * j + 1] + f.y, dn, bias[c + 2 * j + 1]), 0.f);
      o.h2[j] = __floats2half2_rn(ox, oy);
    }
    *(float4*)&out[(size_t)node * COLS + c] = o.f4;
  }
}

// run-length pooling over sorted batch; 32 nodes per wave, lane = column
__global__ void k_pool(const __half* __restrict__ H2, const int* __restrict__ batch,
                       float* __restrict__ psum, float* __restrict__ pcnt, int n) {
  int wv = (blockIdx.x * 256 + threadIdx.x) >> 6;
  int lane = threadIdx.x & 63;
  int start = wv * 32;
  if (start >= n) return;
  int end = min(start + 32, n);
  int curg = batch[start];
  float acc = 0.f;
  int cn = 0;
  for (int i = start; i < end; ++i) {
    int g = batch[i];
    if (g != curg) {
      atomicAdd(&psum[curg * 64 + lane], acc);
      if (lane == 0) atomicAdd(&pcnt[curg], (float)cn);
      acc = 0.f;
      cn = 0;
      curg = g;
    }
    acc += __half2float(H2[(size_t)i * 64 + lane]);
    ++cn;
  }
  atomicAdd(&psum[curg * 64 + lane], acc);
  if (lane == 0) atomicAdd(&pcnt[curg], (float)cn);
}

__global__ void k_final(const float* __restrict__ psum, const float* __restrict__ pcnt,
                        const float* __restrict__ lin_w, const float* __restrict__ lin_b,
                        float* __restrict__ out, int G) {
  int g = blockIdx.x * 64 + threadIdx.x;
  if (g >= G) return;
  float c = fmaxf(pcnt[g], 1.f);
  float s = 0.f;
  for (int i = 0; i < 64; ++i) s += psum[g * 64 + i] * lin_w[i];
  out[g] = s / c + lin_b[0];
}

extern "C" void kernel_launch(void* const* d_in, const int* in_sizes, int n_in,
                              void* d_out, int out_size, void* d_ws, size_t ws_size,
                              hipStream_t stream) {
  const float* x = (const float*)d_in[0];
  const int* edge = (const int*)d_in[1];
  const int* batch = (const int*)d_in[2];
  const float* W1 = (const float*)d_in[3];
  const float* b1 = (const float*)d_in[4];
  const float* W2 = (const float*)d_in[5];
  const float* b2 = (const float*)d_in[6];
  const float* lin_w = (const float*)d_in[7];
  const float* lin_b = (const float*)d_in[8];
  float* out = (float*)d_out;

  const int N = in_sizes[2];
  const int E = in_sizes[1] / 2;
  const int G = out_size;
  const int* esrc_in = edge;       // edge_index[0] = src
  const int* edst_in = edge + E;   // edge_index[1] = dst

  char* w = (char*)d_ws;
  size_t off = 0;
  auto take = [&](size_t bytes) {
    void* p = w + off;
    off += (bytes + 255) & ~(size_t)255;
    return p;
  };
  int* bucket_cnt = (int*)take(256 * 4);
  int* bucket_start = (int*)take(256 * 4);
  int* bucket_cursor = (int*)take(256 * 4);
  int* rowptr = (int*)take((size_t)N * 4);
  int* rowend = (int*)take((size_t)N * 4);
  float* dis = (float*)take((size_t)N * 4);
  int* esrc = (int*)take((size_t)E * 4);
  __half* XW = (__half*)take((size_t)N * 128 * 2);  // fp16; aliases binned
  __half* H = (__half*)take((size_t)N * 128 * 2);   // fp16 H1 / H2
  float* psum = (float*)take((size_t)G * 64 * 4);
  float* pcnt = (float*)take((size_t)G * 4);
  int* binned = (int*)XW;  // E*4 bytes <= N*128*2; dead before gemm128 writes
  (void)ws_size;
  (void)n_in;

  const int NBK = (N + DN - 1) / DN;       // 196 for N=100000 (must be <=256)
  const int PB = (E + 4095) / 4096;        // phase-1 blocks
  int ib = (max(G * 64, NBK) + 255) / 256;

  k_init<<<ib, 256, 0, stream>>>(bucket_cnt, psum, pcnt, NBK, G * 64, G);
  k_hist<<<PB, 1024, 0, stream>>>(edst_in, bucket_cnt, E, NBK);
  k_bscan<<<1, 256, 0, stream>>>(bucket_cnt, bucket_start, bucket_cursor, NBK);
  k_split<<<PB, 1024, 0, stream>>>(esrc_in, edst_in, bucket_cursor, binned, E, NBK);
  k_bucket<<<NBK, 1024, 0, stream>>>(binned, bucket_start, bucket_cnt,
                                     rowptr, rowend, dis, esrc, N);

  int gb = (N + 63) / 64;
  int ab = (int)(((size_t)N * 64 + 255) / 256);

  // layer 1: XW = fp16(dis*(x@W1)), K=128; H = relu(dis*(self+sum)+b1) fp16
  k_gemm<128, 128, float><<<dim3(gb, 2), 256, 0, stream>>>(x, W1, dis, XW, N);
  k_agg<128><<<ab, 256, 0, stream>>>(XW, rowptr, rowend, esrc, dis, b1, H, N);

  // layer 2: XW[:, :64] = fp16(dis*(H@W2)), K=128; H2 into H buffer [N,64]
  k_gemm<64, 128, _Float16><<<dim3(gb, 1), 256, 0, stream>>>(
      (const _Float16*)H, W2, dis, XW, N);
  k_agg<64><<<ab, 256, 0, stream>>>(XW, rowptr, rowend, esrc, dis, b2, H, N);

  // mean-pool + linear head
  int pb = (int)((((size_t)(N + 31) / 32) * 64 + 255) / 256);
  k_pool<<<pb, 256, 0, stream>>>(H, batch, psum, pcnt, N);
  k_final<<<1, 64, 0, stream>>>(psum, pcnt, lin_w, lin_b, out, G);
}

// Round 11
// 312.589 us; speedup vs baseline: 1.6743x; 1.0142x over previous
//
#include <hip/hip_runtime.h>
#include <hip/hip_fp16.h>

// ---------------------------------------------------------------------------
// GCN forward: 2x GCNConv(relu) + global_mean_pool + linear
// CSR via single-pass fixed-capacity bucket multisplit (R11): no hist/scan,
// cursor[k] starts at k*CAP; binned edges packed (src<<9 | local_dst).
// GEMMs are fp16 MFMA, W^T + A staged in LDS, dis[row] in epilogue. All node
// features fp16. Agg = unweighted gather-sum scaled by dis[dst]:
//   out[d] = relu(dis[d]*(XW'[d] + sum XW'[src]) + b)
// R1 scan fix. R2 multi-edge-group agg. R3 fp16 gather. R4 64x64 tiles.
// R5 enorm eliminated. R6 FAILED (locality not bytes). R7 bucket multisplit.
// R8 FAILED K=64. R9 MFMA GEMM (370->333). R10 fp16 H + packed binned (317).
// R11: fixed-CAP buckets (kill hist+bscan), 1-pass 128-col gemm128 (halve x
// refetch), int2 row ranges. agg<128> FETCH ~8x operand = per-XCD L2 floor.
// ---------------------------------------------------------------------------

#define DN 512      // dst nodes per bucket
#define DSHIFT 9    // log2(DN)
#define CAP 10240   // slots per bucket region (mean 8163, sigma~90 -> 23 sigma)

typedef _Float16 half8 __attribute__((ext_vector_type(8)));
typedef float f32x4 __attribute__((ext_vector_type(4)));

__global__ void k_init(int* __restrict__ bucket_cursor, float* __restrict__ psum,
                       float* __restrict__ pcnt, int NBK, int psumN, int G) {
  int i = blockIdx.x * 256 + threadIdx.x;
  if (i < NBK) bucket_cursor[i] = i * CAP;
  if (i < psumN) psum[i] = 0.f;
  if (i < G) pcnt[i] = 0.f;
}

// single-pass multisplit: per-block LDS hist -> one global reservation per
// (block,bucket) -> LDS-cursor scatter of packed (src<<9 | local_dst).
__global__ __launch_bounds__(1024) void k_split(const int* __restrict__ src,
                                                const int* __restrict__ dst,
                                                int* __restrict__ bucket_cursor,
                                                int* __restrict__ binned,
                                                int E, int NBK) {
  __shared__ int h[256];
  __shared__ int lcur[256];
  int t = threadIdx.x;
  if (t < 256) h[t] = 0;
  __syncthreads();
  int base = blockIdx.x * 8192;
  int pk[8], b[8];
  bool val[8];
#pragma unroll
  for (int j = 0; j < 8; ++j) {
    int i = base + j * 1024 + t;
    val[j] = (i < E);
    if (val[j]) {
      int s = src[i], d = dst[i];
      b[j] = d >> DSHIFT;
      pk[j] = (s << DSHIFT) | (d & (DN - 1));
      atomicAdd(&h[b[j]], 1);
    }
  }
  __syncthreads();
  if (t < NBK && h[t] > 0) lcur[t] = atomicAdd(&bucket_cursor[t], h[t]);
  __syncthreads();
#pragma unroll
  for (int j = 0; j < 8; ++j) {
    if (val[j]) {
      int pos = atomicAdd(&lcur[b[j]], 1);
      if (pos < (b[j] + 1) * CAP) binned[pos] = pk[j];  // overflow guard
    }
  }
}

// one block per bucket: LDS per-node count + scan -> rr=(beg,end), dis;
// then LDS-cursor scatter of esrc into the bucket's contiguous region.
__global__ __launch_bounds__(1024) void k_bucket(const int* __restrict__ binned,
                                                 const int* __restrict__ bucket_cursor,
                                                 int2* __restrict__ rr,
                                                 float* __restrict__ dis,
                                                 int* __restrict__ esrc, int N) {
  __shared__ int lcnt[DN];
  __shared__ int lscan[DN];
  int k = blockIdx.x;
  int t = threadIdx.x;
  int bstart = k * CAP;
  int cntk = min(bucket_cursor[k] - bstart, CAP);
  int nbase = k << DSHIFT;
  if (t < DN) lcnt[t] = 0;
  __syncthreads();
  for (int i = t; i < cntk; i += 1024)
    atomicAdd(&lcnt[binned[bstart + i] & (DN - 1)], 1);
  __syncthreads();
  if (t < DN) lscan[t] = lcnt[t];
  __syncthreads();
  for (int off = 1; off < DN; off <<= 1) {
    int v = (t < DN && t >= off) ? lscan[t - off] : 0;
    __syncthreads();
    if (t < DN) lscan[t] += v;
    __syncthreads();
  }
  if (t < DN) {
    int g = nbase + t;
    if (g < N) {
      int inc = lscan[t];
      int c = lcnt[t];
      rr[g] = make_int2(bstart + inc - c, bstart + inc);
      dis[g] = rsqrtf((float)(c + 1));
    }
    lcnt[t] = lscan[t] - lcnt[t];  // reuse as local exclusive cursor
  }
  __syncthreads();
  for (int i = t; i < cntk; i += 1024) {
    int p = binned[bstart + i];
    int slot = atomicAdd(&lcnt[p & (DN - 1)], 1);
    esrc[bstart + slot] = (unsigned)p >> DSHIFT;
  }
}

// out[nrows, COLS] (fp16) = dis[row] * (A[nrows, K] @ W[K, COLS] fp32).
// MFMA 16x16x32_f16. Block = 64 rows x ALL COLS, 4 waves; A-tile and W^T
// staged fp16 in LDS (+8-half pad; COLS=128 -> 52KB, 3 blocks/CU).
// Verified layouts (m89/m120): A[m=lane&15][k=quad*8+j];
// B[k=quad*8+j][n=lane&15]; D col=lane&15, row=quad*4+reg.
template <int COLS, int K, typename AT>
__global__ __launch_bounds__(256) void k_gemm(const AT* __restrict__ A,
                                              const float* __restrict__ W,
                                              const float* __restrict__ dis,
                                              __half* __restrict__ out, int nrows) {
  constexpr int KP = K + 8;  // padded LDS stride (halves)
  __shared__ _Float16 As[64 * KP];
  __shared__ _Float16 Wt[COLS * KP];
  int t = threadIdx.x;
  int row0 = blockIdx.x * 64;

  // stage W^T (fp16), all COLS columns
  {
    constexpr int C4 = COLS / 4;
    for (int i = t; i < K * C4; i += 256) {
      int k = i / C4, c = (i % C4) * 4;
      float4 wv = *(const float4*)&W[(size_t)k * COLS + c];
      Wt[(c + 0) * KP + k] = (_Float16)wv.x;
      Wt[(c + 1) * KP + k] = (_Float16)wv.y;
      Wt[(c + 2) * KP + k] = (_Float16)wv.z;
      Wt[(c + 3) * KP + k] = (_Float16)wv.w;
    }
  }
  // stage A tile (fp16), zero-fill OOB rows
  if constexpr (sizeof(AT) == 4) {
    constexpr int F4 = K / 4;
    for (int id = t; id < 64 * F4; id += 256) {
      int r = id / F4, kq = (id % F4) * 4;
      int grow = row0 + r;
      float4 av = (grow < nrows) ? *(const float4*)&A[(size_t)grow * K + kq]
                                 : make_float4(0.f, 0.f, 0.f, 0.f);
      _Float16* dst = &As[r * KP + kq];
      dst[0] = (_Float16)av.x;
      dst[1] = (_Float16)av.y;
      dst[2] = (_Float16)av.z;
      dst[3] = (_Float16)av.w;
    }
  } else {
    constexpr int H8 = K / 8;
    for (int id = t; id < 64 * H8; id += 256) {
      int r = id / H8, kq = (id % H8) * 8;
      int grow = row0 + r;
      half8 av = (grow < nrows)
                     ? *(const half8*)&A[(size_t)grow * K + kq]
                     : (half8){0, 0, 0, 0, 0, 0, 0, 0};
      *(half8*)&As[r * KP + kq] = av;
    }
  }
  __syncthreads();

  int wave = t >> 6, lane = t & 63;
  int m = lane & 15;     // A row / B col / D col within 16-tile
  int quad = lane >> 4;  // k-group for A/B; row-group for D
  constexpr int NT = COLS / 16;

  f32x4 acc[NT];
#pragma unroll
  for (int ct = 0; ct < NT; ++ct) acc[ct] = (f32x4){0.f, 0.f, 0.f, 0.f};

  const _Float16* arow = &As[(wave * 16 + m) * KP + quad * 8];
#pragma unroll
  for (int ks = 0; ks < K; ks += 32) {
    half8 af = *(const half8*)&arow[ks];
#pragma unroll
    for (int ct = 0; ct < NT; ++ct) {
      half8 bf = *(const half8*)&Wt[(ct * 16 + m) * KP + quad * 8 + ks];
      acc[ct] = __builtin_amdgcn_mfma_f32_16x16x32_f16(af, bf, acc[ct], 0, 0, 0);
    }
  }

  // epilogue: D row = quad*4+j, col = ct*16+m; scale by dis[row], store fp16
#pragma unroll
  for (int j = 0; j < 4; ++j) {
    int gr = row0 + wave * 16 + quad * 4 + j;
    if (gr < nrows) {
      float dn = dis[gr];
#pragma unroll
      for (int ct = 0; ct < NT; ++ct)
        out[(size_t)gr * COLS + ct * 16 + m] = __float2half_rn(acc[ct][j] * dn);
    }
  }
}

// wave per node; COLS/8 lanes per edge-row (16B half8 loads), NG edge groups
// per wave, depth-2 pipeline. H pre-scaled by dis[src]; validity weight {0,1}.
// fp32 accumulate, fp16 output.
template <int COLS>
__global__ __launch_bounds__(256) void k_agg(const __half* __restrict__ H,
                                             const int2* __restrict__ rr,
                                             const int* __restrict__ esrc,
                                             const float* __restrict__ dis,
                                             const float* __restrict__ bias,
                                             __half* __restrict__ out, int n) {
  constexpr int LPE = COLS / 8;  // lanes per edge-row (16 or 8)
  constexpr int NG = 64 / LPE;   // edge groups per wave (4 or 8)
  int node = (blockIdx.x * 256 + threadIdx.x) >> 6;
  if (node >= n) return;
  int lane = threadIdx.x & 63;
  int group = lane / LPE;
  int c = (lane % LPE) * 8;

  float acc[8];
#pragma unroll
  for (int j = 0; j < 8; ++j) acc[j] = 0.f;

  int2 be = rr[node];
  int end = be.y;
  int e0 = be.x + group;
  int e1 = e0 + NG;
  int s0 = 0, s1 = 0;
  float w0 = 0.f, w1 = 0.f;
  if (e0 < end) { s0 = esrc[e0]; w0 = 1.f; }
  if (e1 < end) { s1 = esrc[e1]; w1 = 1.f; }
  while (e0 < end) {
    float4 r0 = *(const float4*)&H[(size_t)s0 * COLS + c];
    float4 r1 = *(const float4*)&H[(size_t)s1 * COLS + c];
    int e2 = e0 + 2 * NG, e3 = e1 + 2 * NG;
    int s2 = 0, s3 = 0;
    float w2 = 0.f, w3 = 0.f;
    if (e2 < end) { s2 = esrc[e2]; w2 = 1.f; }
    if (e3 < end) { s3 = esrc[e3]; w3 = 1.f; }
    {
      union { float4 f4; __half2 h2[4]; } u;
      u.f4 = r0;
#pragma unroll
      for (int j = 0; j < 4; ++j) {
        float2 f = __half22float2(u.h2[j]);
        acc[2 * j + 0] = fmaf(f.x, w0, acc[2 * j + 0]);
        acc[2 * j + 1] = fmaf(f.y, w0, acc[2 * j + 1]);
      }
      u.f4 = r1;
#pragma unroll
      for (int j = 0; j < 4; ++j) {
        float2 f = __half22float2(u.h2[j]);
        acc[2 * j + 0] = fmaf(f.x, w1, acc[2 * j + 0]);
        acc[2 * j + 1] = fmaf(f.y, w1, acc[2 * j + 1]);
      }
    }
    e0 = e2; s0 = s2; w0 = w2;
    e1 = e3; s1 = s3; w1 = w3;
  }
#pragma unroll
  for (int m = LPE; m < 64; m <<= 1) {
#pragma unroll
    for (int j = 0; j < 8; ++j) acc[j] += __shfl_xor(acc[j], m, 64);
  }
  if (group == 0) {
    float dn = dis[node];
    union { float4 f4; __half2 h2[4]; } u;
    u.f4 = *(const float4*)&H[(size_t)node * COLS + c];
    union { __half2 h2[4]; float4 f4; } o;
#pragma unroll
    for (int j = 0; j < 4; ++j) {
      float2 f = __half22float2(u.h2[j]);
      float ox = fmaxf(fmaf(acc[2 * j + 0] + f.x, dn, bias[c + 2 * j + 0]), 0.f);
      float oy = fmaxf(fmaf(acc[2 * j + 1] + f.y, dn, bias[c + 2 * j + 1]), 0.f);
      o.h2[j] = __floats2half2_rn(ox, oy);
    }
    *(float4*)&out[(size_t)node * COLS + c] = o.f4;
  }
}

// run-length pooling over sorted batch; 32 nodes per wave, lane = column
__global__ void k_pool(const __half* __restrict__ H2, const int* __restrict__ batch,
                       float* __restrict__ psum, float* __restrict__ pcnt, int n) {
  int wv = (blockIdx.x * 256 + threadIdx.x) >> 6;
  int lane = threadIdx.x & 63;
  int start = wv * 32;
  if (start >= n) return;
  int end = min(start + 32, n);
  int curg = batch[start];
  float acc = 0.f;
  int cn = 0;
  for (int i = start; i < end; ++i) {
    int g = batch[i];
    if (g != curg) {
      atomicAdd(&psum[curg * 64 + lane], acc);
      if (lane == 0) atomicAdd(&pcnt[curg], (float)cn);
      acc = 0.f;
      cn = 0;
      curg = g;
    }
    acc += __half2float(H2[(size_t)i * 64 + lane]);
    ++cn;
  }
  atomicAdd(&psum[curg * 64 + lane], acc);
  if (lane == 0) atomicAdd(&pcnt[curg], (float)cn);
}

__global__ void k_final(const float* __restrict__ psum, const float* __restrict__ pcnt,
                        const float* __restrict__ lin_w, const float* __restrict__ lin_b,
                        float* __restrict__ out, int G) {
  int g = blockIdx.x * 64 + threadIdx.x;
  if (g >= G) return;
  float c = fmaxf(pcnt[g], 1.f);
  float s = 0.f;
  for (int i = 0; i < 64; ++i) s += psum[g * 64 + i] * lin_w[i];
  out[g] = s / c + lin_b[0];
}

extern "C" void kernel_launch(void* const* d_in, const int* in_sizes, int n_in,
                              void* d_out, int out_size, void* d_ws, size_t ws_size,
                              hipStream_t stream) {
  const float* x = (const float*)d_in[0];
  const int* edge = (const int*)d_in[1];
  const int* batch = (const int*)d_in[2];
  const float* W1 = (const float*)d_in[3];
  const float* b1 = (const float*)d_in[4];
  const float* W2 = (const float*)d_in[5];
  const float* b2 = (const float*)d_in[6];
  const float* lin_w = (const float*)d_in[7];
  const float* lin_b = (const float*)d_in[8];
  float* out = (float*)d_out;

  const int N = in_sizes[2];
  const int E = in_sizes[1] / 2;
  const int G = out_size;
  const int* esrc_in = edge;       // edge_index[0] = src
  const int* edst_in = edge + E;   // edge_index[1] = dst

  char* w = (char*)d_ws;
  size_t off = 0;
  auto take = [&](size_t bytes) {
    void* p = w + off;
    off += (bytes + 255) & ~(size_t)255;
    return p;
  };
  const int NBK = (N + DN - 1) / DN;  // 196 for N=100000 (must be <= 256)
  int* bucket_cursor = (int*)take(256 * 4);
  int2* rr = (int2*)take((size_t)N * 8);
  float* dis = (float*)take((size_t)N * 4);
  int* esrc = (int*)take((size_t)NBK * CAP * 4);    // bucketed, gap layout
  __half* XW = (__half*)take((size_t)N * 128 * 2);  // fp16; aliases binned
  __half* H = (__half*)take((size_t)N * 128 * 2);   // fp16 H1 / H2
  float* psum = (float*)take((size_t)G * 64 * 4);
  float* pcnt = (float*)take((size_t)G * 4);
  int* binned = (int*)XW;  // NBK*CAP*4 = 8MB <= N*128*2; dead before gemm128
  (void)ws_size;
  (void)n_in;

  const int PB = (E + 8191) / 8192;
  int ib = (max(G * 64, NBK) + 255) / 256;

  k_init<<<ib, 256, 0, stream>>>(bucket_cursor, psum, pcnt, NBK, G * 64, G);
  k_split<<<PB, 1024, 0, stream>>>(esrc_in, edst_in, bucket_cursor, binned, E, NBK);
  k_bucket<<<NBK, 1024, 0, stream>>>(binned, bucket_cursor, rr, dis, esrc, N);

  int gb = (N + 63) / 64;
  int ab = (int)(((size_t)N * 64 + 255) / 256);

  // layer 1: XW = fp16(dis*(x@W1)), K=128; H = relu(dis*(self+sum)+b1) fp16
  k_gemm<128, 128, float><<<gb, 256, 0, stream>>>(x, W1, dis, XW, N);
  k_agg<128><<<ab, 256, 0, stream>>>(XW, rr, esrc, dis, b1, H, N);

  // layer 2: XW[:, :64] = fp16(dis*(H@W2)), K=128; H2 into H buffer [N,64]
  k_gemm<64, 128, _Float16><<<gb, 256, 0, stream>>>(
      (const _Float16*)H, W2, dis, XW, N);
  k_agg<64><<<ab, 256, 0, stream>>>(XW, rr, esrc, dis, b2, H, N);

  // mean-pool + linear head
  int pb = (int)((((size_t)(N + 31) / 32) * 64 + 255) / 256);
  k_pool<<<pb, 256, 0, stream>>>(H, batch, psum, pcnt, N);
  k_final<<<1, 64, 0, stream>>>(psum, pcnt, lin_w, lin_b, out, G);
}

// Round 12
// 311.828 us; speedup vs baseline: 1.6784x; 1.0024x over previous
//
#include <hip/hip_runtime.h>
#include <hip/hip_fp16.h>

// ---------------------------------------------------------------------------
// GCN forward: 2x GCNConv(relu) + global_mean_pool + linear
// CSR via single-pass fixed-capacity bucket multisplit; binned edges packed
// (src<<9 | local_dst). GEMMs fp16 MFMA, W^T + A staged in LDS, dis[row] in
// epilogue, D transposed through LDS for coalesced half8 stores (R12).
// All node features fp16. Agg = unweighted gather-sum scaled by dis[dst]:
//   out[d] = relu(dis[d]*(XW'[d] + sum XW'[src]) + b)
// R1 scan fix. R2 multi-edge-group agg. R3 fp16 gather. R4 64x64 tiles.
// R5 enorm eliminated. R6 FAILED (locality not bytes). R7 bucket multisplit.
// R8 FAILED K=64. R9 MFMA GEMM. R10 fp16 H + packed binned. R11 fixed-CAP
// buckets + 1-pass gemm128 (only -4us: agg at 8x-XCD-L2 floor, GEMM cost is
// elsewhere). R12: GEMM epilogue was 12.8M scalar stride-16 2B stores ->
// LDS-transpose (Ds=As reuse, +4 pad) + coalesced half8 row stores.
// ---------------------------------------------------------------------------

#define DN 512      // dst nodes per bucket
#define DSHIFT 9    // log2(DN)
#define CAP 10240   // slots per bucket region (mean 8163, sigma~90 -> 23 sigma)

typedef _Float16 half8 __attribute__((ext_vector_type(8)));
typedef float f32x4 __attribute__((ext_vector_type(4)));

__global__ void k_init(int* __restrict__ bucket_cursor, float* __restrict__ psum,
                       float* __restrict__ pcnt, int NBK, int psumN, int G) {
  int i = blockIdx.x * 256 + threadIdx.x;
  if (i < NBK) bucket_cursor[i] = i * CAP;
  if (i < psumN) psum[i] = 0.f;
  if (i < G) pcnt[i] = 0.f;
}

// single-pass multisplit: per-block LDS hist -> one global reservation per
// (block,bucket) -> LDS-cursor scatter of packed (src<<9 | local_dst).
__global__ __launch_bounds__(1024) void k_split(const int* __restrict__ src,
                                                const int* __restrict__ dst,
                                                int* __restrict__ bucket_cursor,
                                                int* __restrict__ binned,
                                                int E, int NBK) {
  __shared__ int h[256];
  __shared__ int lcur[256];
  int t = threadIdx.x;
  if (t < 256) h[t] = 0;
  __syncthreads();
  int base = blockIdx.x * 8192;
  int pk[8], b[8];
  bool val[8];
#pragma unroll
  for (int j = 0; j < 8; ++j) {
    int i = base + j * 1024 + t;
    val[j] = (i < E);
    if (val[j]) {
      int s = src[i], d = dst[i];
      b[j] = d >> DSHIFT;
      pk[j] = (s << DSHIFT) | (d & (DN - 1));
      atomicAdd(&h[b[j]], 1);
    }
  }
  __syncthreads();
  if (t < NBK && h[t] > 0) lcur[t] = atomicAdd(&bucket_cursor[t], h[t]);
  __syncthreads();
#pragma unroll
  for (int j = 0; j < 8; ++j) {
    if (val[j]) {
      int pos = atomicAdd(&lcur[b[j]], 1);
      if (pos < (b[j] + 1) * CAP) binned[pos] = pk[j];  // overflow guard
    }
  }
}

// one block per bucket: LDS per-node count + scan -> rr=(beg,end), dis;
// then LDS-cursor scatter of esrc into the bucket's contiguous region.
__global__ __launch_bounds__(1024) void k_bucket(const int* __restrict__ binned,
                                                 const int* __restrict__ bucket_cursor,
                                                 int2* __restrict__ rr,
                                                 float* __restrict__ dis,
                                                 int* __restrict__ esrc, int N) {
  __shared__ int lcnt[DN];
  __shared__ int lscan[DN];
  int k = blockIdx.x;
  int t = threadIdx.x;
  int bstart = k * CAP;
  int cntk = min(bucket_cursor[k] - bstart, CAP);
  int nbase = k << DSHIFT;
  if (t < DN) lcnt[t] = 0;
  __syncthreads();
  for (int i = t; i < cntk; i += 1024)
    atomicAdd(&lcnt[binned[bstart + i] & (DN - 1)], 1);
  __syncthreads();
  if (t < DN) lscan[t] = lcnt[t];
  __syncthreads();
  for (int off = 1; off < DN; off <<= 1) {
    int v = (t < DN && t >= off) ? lscan[t - off] : 0;
    __syncthreads();
    if (t < DN) lscan[t] += v;
    __syncthreads();
  }
  if (t < DN) {
    int g = nbase + t;
    if (g < N) {
      int inc = lscan[t];
      int c = lcnt[t];
      rr[g] = make_int2(bstart + inc - c, bstart + inc);
      dis[g] = rsqrtf((float)(c + 1));
    }
    lcnt[t] = lscan[t] - lcnt[t];  // reuse as local exclusive cursor
  }
  __syncthreads();
  for (int i = t; i < cntk; i += 1024) {
    int p = binned[bstart + i];
    int slot = atomicAdd(&lcnt[p & (DN - 1)], 1);
    esrc[bstart + slot] = (unsigned)p >> DSHIFT;
  }
}

// out[nrows, COLS] (fp16) = dis[row] * (A[nrows, K] @ W[K, COLS] fp32).
// MFMA 16x16x32_f16. Block = 64 rows x ALL COLS, 4 waves; A-tile and W^T
// staged fp16 in LDS (+8-half pad). Epilogue: D (dis-scaled fp16) goes
// through LDS (reusing As, stride COLS+4 -> quad-groups on disjoint bank
// octets) and is stored as coalesced half8 rows.
// Verified layouts (m89/m120): A[m=lane&15][k=quad*8+j];
// B[k=quad*8+j][n=lane&15]; D col=lane&15, row=quad*4+reg.
template <int COLS, int K, typename AT>
__global__ __launch_bounds__(256) void k_gemm(const AT* __restrict__ A,
                                              const float* __restrict__ W,
                                              const float* __restrict__ dis,
                                              __half* __restrict__ out, int nrows) {
  constexpr int KP = K + 8;  // padded LDS stride (halves)
  __shared__ _Float16 As[64 * KP];
  __shared__ _Float16 Wt[COLS * KP];
  int t = threadIdx.x;
  int row0 = blockIdx.x * 64;

  // stage W^T (fp16), all COLS columns
  {
    constexpr int C4 = COLS / 4;
    for (int i = t; i < K * C4; i += 256) {
      int k = i / C4, c = (i % C4) * 4;
      float4 wv = *(const float4*)&W[(size_t)k * COLS + c];
      Wt[(c + 0) * KP + k] = (_Float16)wv.x;
      Wt[(c + 1) * KP + k] = (_Float16)wv.y;
      Wt[(c + 2) * KP + k] = (_Float16)wv.z;
      Wt[(c + 3) * KP + k] = (_Float16)wv.w;
    }
  }
  // stage A tile (fp16), zero-fill OOB rows
  if constexpr (sizeof(AT) == 4) {
    constexpr int F4 = K / 4;
    for (int id = t; id < 64 * F4; id += 256) {
      int r = id / F4, kq = (id % F4) * 4;
      int grow = row0 + r;
      float4 av = (grow < nrows) ? *(const float4*)&A[(size_t)grow * K + kq]
                                 : make_float4(0.f, 0.f, 0.f, 0.f);
      _Float16* dst = &As[r * KP + kq];
      dst[0] = (_Float16)av.x;
      dst[1] = (_Float16)av.y;
      dst[2] = (_Float16)av.z;
      dst[3] = (_Float16)av.w;
    }
  } else {
    constexpr int H8 = K / 8;
    for (int id = t; id < 64 * H8; id += 256) {
      int r = id / H8, kq = (id % H8) * 8;
      int grow = row0 + r;
      half8 av = (grow < nrows)
                     ? *(const half8*)&A[(size_t)grow * K + kq]
                     : (half8){0, 0, 0, 0, 0, 0, 0, 0};
      *(half8*)&As[r * KP + kq] = av;
    }
  }
  __syncthreads();

  int wave = t >> 6, lane = t & 63;
  int m = lane & 15;     // A row / B col / D col within 16-tile
  int quad = lane >> 4;  // k-group for A/B; row-group for D
  constexpr int NT = COLS / 16;

  f32x4 acc[NT];
#pragma unroll
  for (int ct = 0; ct < NT; ++ct) acc[ct] = (f32x4){0.f, 0.f, 0.f, 0.f};

  const _Float16* arow = &As[(wave * 16 + m) * KP + quad * 8];
#pragma unroll
  for (int ks = 0; ks < K; ks += 32) {
    half8 af = *(const half8*)&arow[ks];
#pragma unroll
    for (int ct = 0; ct < NT; ++ct) {
      half8 bf = *(const half8*)&Wt[(ct * 16 + m) * KP + quad * 8 + ks];
      acc[ct] = __builtin_amdgcn_mfma_f32_16x16x32_f16(af, bf, acc[ct], 0, 0, 0);
    }
  }

  // epilogue: dis-scale -> LDS transpose (reuse As; DP=COLS+4 avoids quad
  // bank collisions) -> coalesced half8 row stores.
  __syncthreads();  // all As reads done
  _Float16* Ds = As;
  constexpr int DP = COLS + 4;
#pragma unroll
  for (int j = 0; j < 4; ++j) {
    int rl = wave * 16 + quad * 4 + j;
    int gr = row0 + rl;
    float dn = (gr < nrows) ? dis[gr] : 0.f;
#pragma unroll
    for (int ct = 0; ct < NT; ++ct)
      Ds[rl * DP + ct * 16 + m] = (_Float16)(acc[ct][j] * dn);
  }
  __syncthreads();
  constexpr int C8 = COLS / 8;
  for (int id = t; id < 64 * C8; id += 256) {
    int r = id / C8, c8 = (id % C8) * 8;
    int gr = row0 + r;
    if (gr < nrows)
      *(half8*)&out[(size_t)gr * COLS + c8] = *(const half8*)&Ds[r * DP + c8];
  }
}

// wave per node; COLS/8 lanes per edge-row (16B half8 loads), NG edge groups
// per wave, depth-2 pipeline. H pre-scaled by dis[src]; validity weight {0,1}.
// fp32 accumulate, fp16 output.
template <int COLS>
__global__ __launch_bounds__(256) void k_agg(const __half* __restrict__ H,
                                             const int2* __restrict__ rr,
                                             const int* __restrict__ esrc,
                                             const float* __restrict__ dis,
                                             const float* __restrict__ bias,
                                             __half* __restrict__ out, int n) {
  constexpr int LPE = COLS / 8;  // lanes per edge-row (16 or 8)
  constexpr int NG = 64 / LPE;   // edge groups per wave (4 or 8)
  int node = (blockIdx.x * 256 + threadIdx.x) >> 6;
  if (node >= n) return;
  int lane = threadIdx.x & 63;
  int group = lane / LPE;
  int c = (lane % LPE) * 8;

  float acc[8];
#pragma unroll
  for (int j = 0; j < 8; ++j) acc[j] = 0.f;

  int2 be = rr[node];
  int end = be.y;
  int e0 = be.x + group;
  int e1 = e0 + NG;
  int s0 = 0, s1 = 0;
  float w0 = 0.f, w1 = 0.f;
  if (e0 < end) { s0 = esrc[e0]; w0 = 1.f; }
  if (e1 < end) { s1 = esrc[e1]; w1 = 1.f; }
  while (e0 < end) {
    float4 r0 = *(const float4*)&H[(size_t)s0 * COLS + c];
    float4 r1 = *(const float4*)&H[(size_t)s1 * COLS + c];
    int e2 = e0 + 2 * NG, e3 = e1 + 2 * NG;
    int s2 = 0, s3 = 0;
    float w2 = 0.f, w3 = 0.f;
    if (e2 < end) { s2 = esrc[e2]; w2 = 1.f; }
    if (e3 < end) { s3 = esrc[e3]; w3 = 1.f; }
    {
      union { float4 f4; __half2 h2[4]; } u;
      u.f4 = r0;
#pragma unroll
      for (int j = 0; j < 4; ++j) {
        float2 f = __half22float2(u.h2[j]);
        acc[2 * j + 0] = fmaf(f.x, w0, acc[2 * j + 0]);
        acc[2 * j + 1] = fmaf(f.y, w0, acc[2 * j + 1]);
      }
      u.f4 = r1;
#pragma unroll
      for (int j = 0; j < 4; ++j) {
        float2 f = __half22float2(u.h2[j]);
        acc[2 * j + 0] = fmaf(f.x, w1, acc[2 * j + 0]);
        acc[2 * j + 1] = fmaf(f.y, w1, acc[2 * j + 1]);
      }
    }
    e0 = e2; s0 = s2; w0 = w2;
    e1 = e3; s1 = s3; w1 = w3;
  }
#pragma unroll
  for (int m = LPE; m < 64; m <<= 1) {
#pragma unroll
    for (int j = 0; j < 8; ++j) acc[j] += __shfl_xor(acc[j], m, 64);
  }
  if (group == 0) {
    float dn = dis[node];
    union { float4 f4; __half2 h2[4]; } u;
    u.f4 = *(const float4*)&H[(size_t)node * COLS + c];
    union { __half2 h2[4]; float4 f4; } o;
#pragma unroll
    for (int j = 0; j < 4; ++j) {
      float2 f = __half22float2(u.h2[j]);
      float ox = fmaxf(fmaf(acc[2 * j + 0] + f.x, dn, bias[c + 2 * j + 0]), 0.f);
      float oy = fmaxf(fmaf(acc[2 * j + 1] + f.y, dn, bias[c + 2 * j + 1]), 0.f);
      o.h2[j] = __floats2half2_rn(ox, oy);
    }
    *(float4*)&out[(size_t)node * COLS + c] = o.f4;
  }
}

// run-length pooling over sorted batch; 32 nodes per wave, lane = column
__global__ void k_pool(const __half* __restrict__ H2, const int* __restrict__ batch,
                       float* __restrict__ psum, float* __restrict__ pcnt, int n) {
  int wv = (blockIdx.x * 256 + threadIdx.x) >> 6;
  int lane = threadIdx.x & 63;
  int start = wv * 32;
  if (start >= n) return;
  int end = min(start + 32, n);
  int curg = batch[start];
  float acc = 0.f;
  int cn = 0;
  for (int i = start; i < end; ++i) {
    int g = batch[i];
    if (g != curg) {
      atomicAdd(&psum[curg * 64 + lane], acc);
      if (lane == 0) atomicAdd(&pcnt[curg], (float)cn);
      acc = 0.f;
      cn = 0;
      curg = g;
    }
    acc += __half2float(H2[(size_t)i * 64 + lane]);
    ++cn;
  }
  atomicAdd(&psum[curg * 64 + lane], acc);
  if (lane == 0) atomicAdd(&pcnt[curg], (float)cn);
}

__global__ void k_final(const float* __restrict__ psum, const float* __restrict__ pcnt,
                        const float* __restrict__ lin_w, const float* __restrict__ lin_b,
                        float* __restrict__ out, int G) {
  int g = blockIdx.x * 64 + threadIdx.x;
  if (g >= G) return;
  float c = fmaxf(pcnt[g], 1.f);
  float s = 0.f;
  for (int i = 0; i < 64; ++i) s += psum[g * 64 + i] * lin_w[i];
  out[g] = s / c + lin_b[0];
}

extern "C" void kernel_launch(void* const* d_in, const int* in_sizes, int n_in,
                              void* d_out, int out_size, void* d_ws, size_t ws_size,
                              hipStream_t stream) {
  const float* x = (const float*)d_in[0];
  const int* edge = (const int*)d_in[1];
  const int* batch = (const int*)d_in[2];
  const float* W1 = (const float*)d_in[3];
  const float* b1 = (const float*)d_in[4];
  const float* W2 = (const float*)d_in[5];
  const float* b2 = (const float*)d_in[6];
  const float* lin_w = (const float*)d_in[7];
  const float* lin_b = (const float*)d_in[8];
  float* out = (float*)d_out;

  const int N = in_sizes[2];
  const int E = in_sizes[1] / 2;
  const int G = out_size;
  const int* esrc_in = edge;       // edge_index[0] = src
  const int* edst_in = edge + E;   // edge_index[1] = dst

  char* w = (char*)d_ws;
  size_t off = 0;
  auto take = [&](size_t bytes) {
    void* p = w + off;
    off += (bytes + 255) & ~(size_t)255;
    return p;
  };
  const int NBK = (N + DN - 1) / DN;  // 196 for N=100000 (must be <= 256)
  int* bucket_cursor = (int*)take(256 * 4);
  int2* rr = (int2*)take((size_t)N * 8);
  float* dis = (float*)take((size_t)N * 4);
  int* esrc = (int*)take((size_t)NBK * CAP * 4);    // bucketed, gap layout
  __half* XW = (__half*)take((size_t)N * 128 * 2);  // fp16; aliases binned
  __half* H = (__half*)take((size_t)N * 128 * 2);   // fp16 H1 / H2
  float* psum = (float*)take((size_t)G * 64 * 4);
  float* pcnt = (float*)take((size_t)G * 4);
  int* binned = (int*)XW;  // NBK*CAP*4 = 8MB <= N*128*2; dead before gemm128
  (void)ws_size;
  (void)n_in;

  const int PB = (E + 8191) / 8192;
  int ib = (max(G * 64, NBK) + 255) / 256;

  k_init<<<ib, 256, 0, stream>>>(bucket_cursor, psum, pcnt, NBK, G * 64, G);
  k_split<<<PB, 1024, 0, stream>>>(esrc_in, edst_in, bucket_cursor, binned, E, NBK);
  k_bucket<<<NBK, 1024, 0, stream>>>(binned, bucket_cursor, rr, dis, esrc, N);

  int gb = (N + 63) / 64;
  int ab = (int)(((size_t)N * 64 + 255) / 256);

  // layer 1: XW = fp16(dis*(x@W1)), K=128; H = relu(dis*(self+sum)+b1) fp16
  k_gemm<128, 128, float><<<gb, 256, 0, stream>>>(x, W1, dis, XW, N);
  k_agg<128><<<ab, 256, 0, stream>>>(XW, rr, esrc, dis, b1, H, N);

  // layer 2: XW[:, :64] = fp16(dis*(H@W2)), K=128; H2 into H buffer [N,64]
  k_gemm<64, 128, _Float16><<<gb, 256, 0, stream>>>(
      (const _Float16*)H, W2, dis, XW, N);
  k_agg<64><<<ab, 256, 0, stream>>>(XW, rr, esrc, dis, b2, H, N);

  // mean-pool + linear head
  int pb = (int)((((size_t)(N + 31) / 32) * 64 + 255) / 256);
  k_pool<<<pb, 256, 0, stream>>>(H, batch, psum, pcnt, N);
  k_final<<<1, 64, 0, stream>>>(psum, pcnt, lin_w, lin_b, out, G);
}